// Round 10
// baseline (326.305 us; speedup 1.0000x reference)
//
#include <hip/hip_runtime.h>
#include <math.h>

#define BATCH 512
#define MAXLEN 80
#define LATENT 10
#define HID 64
#define NSTEPS 100
#define DT 0.01f
#define OUTOFF (BATCH * MAXLEN * LATENT)

typedef float v2f __attribute__((ext_vector_type(2)));

__device__ __forceinline__ v2f mkv(float a, float b) { v2f r; r.x = a; r.y = b; return r; }
__device__ __forceinline__ v2f bc(float a) { v2f r; r.x = a; r.y = a; return r; }
__device__ __forceinline__ v2f fma2(v2f a, v2f b, v2f c) { return __builtin_elementwise_fma(a, b, c); }

template <int CTRL>
__device__ __forceinline__ v2f dppadd(v2f x) {
    v2f t;
    t.x = __int_as_float(__builtin_amdgcn_update_dpp(0, __float_as_int(x.x), CTRL, 0xF, 0xF, false));
    t.y = __int_as_float(__builtin_amdgcn_update_dpp(0, __float_as_int(x.y), CTRL, 0xF, 0xF, false));
    return x + t;
}
// all-reduce across a 16-lane group (aligned with DPP row=16):
// xor1, xor2, then cross-quad (half-mirror) and cross-8 (row-mirror);
// mirrors are valid reductions because earlier stages make each
// quad/oct uniform.
__device__ __forceinline__ v2f allsum16(v2f x) {
    x = dppadd<0xB1>(x);    // quad_perm [1,0,3,2]  : xor 1
    x = dppadd<0x4E>(x);    // quad_perm [2,3,0,1]  : xor 2
    x = dppadd<0x141>(x);   // row_half_mirror      : cross-quad in 8
    x = dppadd<0x140>(x);   // row_mirror           : cross-8 in 16
    return x;
}

// 16 lanes per chain: lane owns hidden units j = 4*lam .. 4*lam+3
// (88 weight floats = 44 v2f per lane -> fits the ~124-VGPR budget the
// allocator actually grants; R5-R9 showed a 176-float set gets
// rematerialized/reloaded every step no matter what) and output dim
// d = lam for lam < 10.

#define W1ROW(k, xk) { \
    v2f xb = bc(xk); \
    hA = fma2(xb, w1A##k, hA); hB = fma2(xb, w1B##k, hB); }

#define W2ROW(q, hs) { \
    v2f hb = bc(hs); \
    a01 = fma2(hb, w2##q##_0, a01); a23 = fma2(hb, w2##q##_1, a23); \
    a45 = fma2(hb, w2##q##_2, a45); a67 = fma2(hb, w2##q##_3, a67); \
    a89 = fma2(hb, w2##q##_4, a89); }

#define DECLW1(k) \
    v2f w1A##k, w1B##k; { \
        const v2f* r_ = (const v2f*)&W1[(k) * HID + j4]; \
        w1A##k = r_[0]; w1B##k = r_[1]; }

#define DECLW2(q) \
    v2f w2##q##_0, w2##q##_1, w2##q##_2, w2##q##_3, w2##q##_4; { \
        const v2f* r_ = (const v2f*)(W2 + (j4 + (q)) * LATENT); \
        w2##q##_0 = r_[0] * cvt01; w2##q##_1 = r_[1] * cvt23; \
        w2##q##_2 = r_[2] * cvt45; w2##q##_3 = r_[3] * cvt67; \
        w2##q##_4 = r_[4] * cvt89; }

__global__ __launch_bounds__(256) void vae_sde_kernel(
    const float* __restrict__ z_mean, const float* __restrict__ z_log_var,
    const float* __restrict__ W1, const float* __restrict__ b1,
    const float* __restrict__ W2, const float* __restrict__ b2,
    const float* __restrict__ noise, float* __restrict__ out)
{
    __shared__ float sMU[16][LATENT];
    __shared__ float sSG[16][LATENT];

    const int tid  = threadIdx.x;
    const int g    = blockIdx.x * 256 + tid;
    const int c    = g >> 4;          // chain id
    const int lam  = tid & 15;        // lane within 16-lane group
    const int cb   = tid >> 4;        // chain within block (0..15)
    const int l    = c >> 9;
    const int bb   = c & 511;
    const int base = (bb * MAXLEN + l) * LATENT;
    const bool lp  = (l > 0);
    const bool own = (lam < LATENT);
    const int  d   = own ? lam : (lam & 7);   // non-owners: finite dummy dim
    const float sqdt = sqrtf(DT);

    // per-owned-dim setup
    float mur, is_, cw, icv, rb2v, mb, er = 0.f, xsel;
    {
        float zm  = z_mean[base + d];
        float zmp = lp ? z_mean[base - LATENT + d] : 0.f;
        float zv  = z_log_var[base + d];
        float zvp = lp ? z_log_var[base - LATENT + d] : 0.f;
        float mx  = fmaxf(zv, zvp);
        float sg  = mx + log1pf(expf(-fabsf(zv - zvp)));
        float sd  = expf(0.5f * sg);
        float cvv = 0.5f * DT * sd * sd;
        mur = zm - zmp; is_ = 1.f / sg; cw = sd * sqdt; icv = 1.f / cvv;
        rb2v = b2[d]; mb = fmaf(cvv, rb2v, mur * DT);
        xsel = mur;
        if (own) { sMU[cb][d] = mur; sSG[cb][d] = sg; }
    }
    __syncthreads();

    // replicated per-chain state
    v2f xt01 = mkv(sMU[cb][0], sMU[cb][1]);
    v2f xt23 = mkv(sMU[cb][2], sMU[cb][3]);
    v2f xt45 = mkv(sMU[cb][4], sMU[cb][5]);
    v2f xt67 = mkv(sMU[cb][6], sMU[cb][7]);
    v2f xt89 = mkv(sMU[cb][8], sMU[cb][9]);
    const v2f cvt01 = mkv(0.5f * DT * expf(sSG[cb][0]), 0.5f * DT * expf(sSG[cb][1]));
    const v2f cvt23 = mkv(0.5f * DT * expf(sSG[cb][2]), 0.5f * DT * expf(sSG[cb][3]));
    const v2f cvt45 = mkv(0.5f * DT * expf(sSG[cb][4]), 0.5f * DT * expf(sSG[cb][5]));
    const v2f cvt67 = mkv(0.5f * DT * expf(sSG[cb][6]), 0.5f * DT * expf(sSG[cb][7]));
    const v2f cvt89 = mkv(0.5f * DT * expf(sSG[cb][8]), 0.5f * DT * expf(sSG[cb][9]));

    const int j4 = lam * 4;
    v2f b1A, b1B;
    { const v2f* r_ = (const v2f*)&b1[j4]; b1A = r_[0]; b1B = r_[1]; }

    DECLW1(0) DECLW1(1) DECLW1(2) DECLW1(3) DECLW1(4) DECLW1(5)
    DECLW1(6) DECLW1(7) DECLW1(8) DECLW1(9) DECLW1(10)
    DECLW2(0) DECLW2(1) DECLW2(2) DECLW2(3)

    const v2f mk01 = mkv(lam == 0 ? 1.f : 0.f, lam == 1 ? 1.f : 0.f);
    const v2f mk23 = mkv(lam == 2 ? 1.f : 0.f, lam == 3 ? 1.f : 0.f);
    const v2f mk45 = mkv(lam == 4 ? 1.f : 0.f, lam == 5 ? 1.f : 0.f);
    const v2f mk67 = mkv(lam == 6 ? 1.f : 0.f, lam == 7 ? 1.f : 0.f);
    const v2f mk89 = mkv(lam == 8 ? 1.f : 0.f, lam == 9 ? 1.f : 0.f);

    const float* npp = noise + ((size_t)l * NSTEPS * BATCH + bb) * LATENT + d;
    float nz = npp[0];

    #pragma unroll 1
    for (int s = 0; s < NSTEPS; ++s) {
        const float cu = nz;
        if (s + 1 < NSTEPS) {
            npp += BATCH * LATENT;
            nz = *npp;
        }
        const float tt = (float)(l + s) * DT;

        // h = relu([xt, t] @ W1 + b1) — lane's 4-unit slice
        v2f hA = fma2(bc(xt01.x), w1A0, b1A);
        v2f hB = fma2(bc(xt01.x), w1B0, b1B);
        W1ROW(1, xt01.y) W1ROW(2, xt23.x) W1ROW(3, xt23.y) W1ROW(4, xt45.x)
        W1ROW(5, xt45.y) W1ROW(6, xt67.x) W1ROW(7, xt67.y) W1ROW(8, xt89.x)
        W1ROW(9, xt89.y) W1ROW(10, tt)
        const v2f zero2 = mkv(0.f, 0.f);
        hA = __builtin_elementwise_max(hA, zero2);
        hB = __builtin_elementwise_max(hB, zero2);

        // partial cv_d * (W2 h)_d over the 4 owned hidden units
        v2f a01 = w20_0 * bc(hA.x), a23 = w20_1 * bc(hA.x);
        v2f a45 = w20_2 * bc(hA.x), a67 = w20_3 * bc(hA.x);
        v2f a89 = w20_4 * bc(hA.x);
        W2ROW(1, hA.y) W2ROW(2, hB.x) W2ROW(3, hB.y)

        // owner folds in base term: mu*dt + cv*b2 + cw*dW
        const float ob = fmaf(cw, cu, mb);
        a01 = fma2(mk01, bc(ob), a01);
        a23 = fma2(mk23, bc(ob), a23);
        a45 = fma2(mk45, bc(ob), a45);
        a67 = fma2(mk67, bc(ob), a67);
        a89 = fma2(mk89, bc(ob), a89);

        // 16-lane all-reduce -> a* = delta_xt replicated
        a01 = allsum16(a01); a23 = allsum16(a23); a45 = allsum16(a45);
        a67 = allsum16(a67); a89 = allsum16(a89);

        // owner extracts its dim's delta (mask dot)
        v2f t = a01 * mk01;
        t = fma2(a23, mk23, t);
        t = fma2(a45, mk45, t);
        t = fma2(a67, mk67, t);
        t = fma2(a89, mk89, t);
        const float ds = t.x + t.y;

        // error accumulation at owner
        {
            const float ld = (mur - xsel) * is_;
            const float sc = fmaf(ds - ob, icv, rb2v);
            const float df = ld - sc;
            er = fmaf(df, df, er);
            xsel += ds;
        }

        // replicated xt update
        xt01 += a01; xt23 += a23; xt45 += a45; xt67 += a67; xt89 += a89;
    }

    if (own) {
        out[base + lam]          = xsel;
        out[OUTOFF + base + lam] = er * (1.0f / NSTEPS);
    }
}

extern "C" void kernel_launch(void* const* d_in, const int* in_sizes, int n_in,
                              void* d_out, int out_size, void* d_ws, size_t ws_size,
                              hipStream_t stream) {
    const float* z_mean    = (const float*)d_in[0];
    const float* z_log_var = (const float*)d_in[1];
    const float* W1 = (const float*)d_in[2];
    const float* b1 = (const float*)d_in[3];
    const float* W2 = (const float*)d_in[4];
    const float* b2 = (const float*)d_in[5];
    const float* noise = (const float*)d_in[6];
    float* out = (float*)d_out;

    // 40960 chains x 16 lanes = 655360 threads = 2560 blocks of 256
    vae_sde_kernel<<<dim3(2560), dim3(256), 0, stream>>>(
        z_mean, z_log_var, W1, b1, W2, b2, noise, out);
}

// Round 11
// 208.920 us; speedup vs baseline: 1.5619x; 1.5619x over previous
//
#include <hip/hip_runtime.h>
#include <math.h>

#define BATCH 512
#define MAXLEN 80
#define LATENT 10
#define HID 64
#define NSTEPS 100
#define DT 0.01f
#define OUTOFF (BATCH * MAXLEN * LATENT)

typedef float v2f __attribute__((ext_vector_type(2)));

__device__ __forceinline__ v2f mkv(float a, float b) { v2f r; r.x = a; r.y = b; return r; }
__device__ __forceinline__ v2f bc(float a) { v2f r; r.x = a; r.y = a; return r; }
__device__ __forceinline__ v2f fma2(v2f a, v2f b, v2f c) { return __builtin_elementwise_fma(a, b, c); }

// Non-rematerializable register copy. The RA treats loads from read-only
// global memory as trivially remattable and re-emits load+addressing every
// loop iteration (R5-R10: ~200 extra issue slots/step, immune to pins and
// occupancy hints). A volatile asm cannot be re-executed, so its outputs
// MUST stay register-resident (or visibly spill to scratch).
__device__ __forceinline__ v2f pinv(v2f x) {
    float ax = x.x, ay = x.y, a, b;
    asm volatile("v_mov_b32 %0, %2\n\tv_mov_b32 %1, %3"
                 : "=v"(a), "=v"(b) : "v"(ax), "v"(ay));
    return mkv(a, b);
}

template <int CTRL>
__device__ __forceinline__ v2f dppadd(v2f x) {
    v2f t;
    t.x = __int_as_float(__builtin_amdgcn_update_dpp(0, __float_as_int(x.x), CTRL, 0xF, 0xF, false));
    t.y = __int_as_float(__builtin_amdgcn_update_dpp(0, __float_as_int(x.y), CTRL, 0xF, 0xF, false));
    return x + t;
}
// all-reduce over 8-lane group: xor1, xor2, mirror
__device__ __forceinline__ v2f allsum(v2f x) {
    x = dppadd<0xB1>(x);    // quad_perm [1,0,3,2]
    x = dppadd<0x4E>(x);    // quad_perm [2,3,0,1]
    x = dppadd<0x141>(x);   // row_half_mirror
    return x;
}

#define HKP(k, xk) { \
    v2f xb = bc(xk); \
    h01 = fma2(xb, w1_##k##_0, h01); h23 = fma2(xb, w1_##k##_1, h23); \
    h45 = fma2(xb, w1_##k##_2, h45); h67 = fma2(xb, w1_##k##_3, h67); }

#define W2P(q, hs) { \
    v2f hb = bc(hs); \
    a01 = fma2(hb, w2_##q##_0, a01); a23 = fma2(hb, w2_##q##_1, a23); \
    a45 = fma2(hb, w2_##q##_2, a45); a67 = fma2(hb, w2_##q##_3, a67); \
    a89 = fma2(hb, w2_##q##_4, a89); }

#define DECLW1(k) \
    v2f w1_##k##_0, w1_##k##_1, w1_##k##_2, w1_##k##_3; { \
        const v2f* r_ = (const v2f*)&W1[(k) * HID + j8]; \
        w1_##k##_0 = pinv(r_[0]); w1_##k##_1 = pinv(r_[1]); \
        w1_##k##_2 = pinv(r_[2]); w1_##k##_3 = pinv(r_[3]); }

#define DECLW2(q) \
    v2f w2_##q##_0, w2_##q##_1, w2_##q##_2, w2_##q##_3, w2_##q##_4; { \
        const v2f* r_ = (const v2f*)(W2 + (j8 + (q)) * LATENT); \
        w2_##q##_0 = pinv(r_[0] * cvt01); w2_##q##_1 = pinv(r_[1] * cvt23); \
        w2_##q##_2 = pinv(r_[2] * cvt45); w2_##q##_3 = pinv(r_[3] * cvt67); \
        w2_##q##_4 = pinv(r_[4] * cvt89); }

__global__ __attribute__((amdgpu_waves_per_eu(2, 2))) __launch_bounds__(256)
void vae_sde_kernel(
    const float* __restrict__ z_mean, const float* __restrict__ z_log_var,
    const float* __restrict__ W1, const float* __restrict__ b1,
    const float* __restrict__ W2, const float* __restrict__ b2,
    const float* __restrict__ noise, float* __restrict__ out)
{
    __shared__ float sMU[32][LATENT];
    __shared__ float sSG[32][LATENT];

    const int tid  = threadIdx.x;
    const int g    = blockIdx.x * 256 + tid;
    const int c    = g >> 3;
    const int lane = tid & 7;
    const int cb   = tid >> 3;
    const int l    = c >> 9;
    const int bb   = c & 511;
    const int base = (bb * MAXLEN + l) * LATENT;
    const bool lp   = (l > 0);
    const bool has2 = (lane < 2);
    const float sqdt = sqrtf(DT);

    float mur0, is0, cw0, icv0, rb2_0, mb0, er0 = 0.f, xsel0;
    float mur1 = 0.f, is1 = 0.f, cw1 = 0.f, icv1 = 0.f, rb2_1 = 0.f,
          mb1 = 0.f, er1 = 0.f, xsel1 = 0.f;

    {
        const int d = lane;
        float zm  = z_mean[base + d];
        float zmp = lp ? z_mean[base - LATENT + d] : 0.f;
        float zv  = z_log_var[base + d];
        float zvp = lp ? z_log_var[base - LATENT + d] : 0.f;
        float mx  = fmaxf(zv, zvp);
        float sg  = mx + log1pf(expf(-fabsf(zv - zvp)));
        float sd  = expf(0.5f * sg);
        float cvv = 0.5f * DT * sd * sd;
        mur0 = zm - zmp; is0 = 1.f / sg; cw0 = sd * sqdt; icv0 = 1.f / cvv;
        rb2_0 = b2[d]; mb0 = fmaf(cvv, rb2_0, mur0 * DT);
        xsel0 = mur0;
        sMU[cb][d] = mur0;
        sSG[cb][d] = sg;
    }
    if (has2) {
        const int d = 8 + lane;
        float zm  = z_mean[base + d];
        float zmp = lp ? z_mean[base - LATENT + d] : 0.f;
        float zv  = z_log_var[base + d];
        float zvp = lp ? z_log_var[base - LATENT + d] : 0.f;
        float mx  = fmaxf(zv, zvp);
        float sg  = mx + log1pf(expf(-fabsf(zv - zvp)));
        float sd  = expf(0.5f * sg);
        float cvv = 0.5f * DT * sd * sd;
        mur1 = zm - zmp; is1 = 1.f / sg; cw1 = sd * sqdt; icv1 = 1.f / cvv;
        rb2_1 = b2[d]; mb1 = fmaf(cvv, rb2_1, mur1 * DT);
        xsel1 = mur1;
        sMU[cb][d] = mur1;
        sSG[cb][d] = sg;
    }
    __syncthreads();

    v2f xt01 = mkv(sMU[cb][0], sMU[cb][1]);
    v2f xt23 = mkv(sMU[cb][2], sMU[cb][3]);
    v2f xt45 = mkv(sMU[cb][4], sMU[cb][5]);
    v2f xt67 = mkv(sMU[cb][6], sMU[cb][7]);
    v2f xt89 = mkv(sMU[cb][8], sMU[cb][9]);
    const v2f cvt01 = mkv(0.5f * DT * expf(sSG[cb][0]), 0.5f * DT * expf(sSG[cb][1]));
    const v2f cvt23 = mkv(0.5f * DT * expf(sSG[cb][2]), 0.5f * DT * expf(sSG[cb][3]));
    const v2f cvt45 = mkv(0.5f * DT * expf(sSG[cb][4]), 0.5f * DT * expf(sSG[cb][5]));
    const v2f cvt67 = mkv(0.5f * DT * expf(sSG[cb][6]), 0.5f * DT * expf(sSG[cb][7]));
    const v2f cvt89 = mkv(0.5f * DT * expf(sSG[cb][8]), 0.5f * DT * expf(sSG[cb][9]));

    const int j8 = lane * 8;
    v2f b1_0, b1_1, b1_2, b1_3;
    { const v2f* r_ = (const v2f*)&b1[j8];
      b1_0 = pinv(r_[0]); b1_1 = pinv(r_[1]); b1_2 = pinv(r_[2]); b1_3 = pinv(r_[3]); }

    DECLW1(0) DECLW1(1) DECLW1(2) DECLW1(3) DECLW1(4) DECLW1(5)
    DECLW1(6) DECLW1(7) DECLW1(8) DECLW1(9) DECLW1(10)
    DECLW2(0) DECLW2(1) DECLW2(2) DECLW2(3)
    DECLW2(4) DECLW2(5) DECLW2(6) DECLW2(7)

    const v2f mk01 = pinv(mkv(lane == 0 ? 1.f : 0.f, lane == 1 ? 1.f : 0.f));
    const v2f mk23 = pinv(mkv(lane == 2 ? 1.f : 0.f, lane == 3 ? 1.f : 0.f));
    const v2f mk45 = pinv(mkv(lane == 4 ? 1.f : 0.f, lane == 5 ? 1.f : 0.f));
    const v2f mk67 = pinv(mkv(lane == 6 ? 1.f : 0.f, lane == 7 ? 1.f : 0.f));
    const v2f mk89 = mk01;

    const float* np0 = noise + ((size_t)l * NSTEPS * BATCH + bb) * LATENT + lane;
    const float* np1 = np0 + (has2 ? 8 : 0);
    float nz0 = *np0;
    float nz1 = *np1;

    const v2f zero2 = mkv(0.f, 0.f);

    #pragma unroll 1
    for (int s = 0; s < NSTEPS; ++s) {
        const float cu0 = nz0, cu1 = nz1;
        if (s + 1 < NSTEPS) {
            np0 += BATCH * LATENT;
            np1 += BATCH * LATENT;
            nz0 = *np0;
            nz1 = *np1;
        }
        const float tt = (float)(l + s) * DT;

        v2f h01 = fma2(bc(xt01.x), w1_0_0, b1_0);
        v2f h23 = fma2(bc(xt01.x), w1_0_1, b1_1);
        v2f h45 = fma2(bc(xt01.x), w1_0_2, b1_2);
        v2f h67 = fma2(bc(xt01.x), w1_0_3, b1_3);
        HKP(1, xt01.y) HKP(2, xt23.x) HKP(3, xt23.y) HKP(4, xt45.x)
        HKP(5, xt45.y) HKP(6, xt67.x) HKP(7, xt67.y) HKP(8, xt89.x)
        HKP(9, xt89.y) HKP(10, tt)
        h01 = __builtin_elementwise_max(h01, zero2);
        h23 = __builtin_elementwise_max(h23, zero2);
        h45 = __builtin_elementwise_max(h45, zero2);
        h67 = __builtin_elementwise_max(h67, zero2);

        v2f a01 = w2_0_0 * bc(h01.x), a23 = w2_0_1 * bc(h01.x);
        v2f a45 = w2_0_2 * bc(h01.x), a67 = w2_0_3 * bc(h01.x);
        v2f a89 = w2_0_4 * bc(h01.x);
        W2P(1, h01.y) W2P(2, h23.x) W2P(3, h23.y) W2P(4, h45.x)
        W2P(5, h45.y) W2P(6, h67.x) W2P(7, h67.y)

        const float ob0 = fmaf(cw0, cu0, mb0);
        const float ob1 = fmaf(cw1, cu1, mb1);
        a01 = fma2(mk01, bc(ob0), a01);
        a23 = fma2(mk23, bc(ob0), a23);
        a45 = fma2(mk45, bc(ob0), a45);
        a67 = fma2(mk67, bc(ob0), a67);
        a89 = fma2(mk89, bc(ob1), a89);

        a01 = allsum(a01); a23 = allsum(a23); a45 = allsum(a45);
        a67 = allsum(a67); a89 = allsum(a89);

        v2f t = a01 * mk01;
        t = fma2(a23, mk23, t);
        t = fma2(a45, mk45, t);
        t = fma2(a67, mk67, t);
        const float ds0 = t.x + t.y;
        v2f t9 = a89 * mk89;
        const float ds1 = t9.x + t9.y;

        {
            const float ld = (mur0 - xsel0) * is0;
            const float sc = fmaf(ds0 - ob0, icv0, rb2_0);
            const float df = ld - sc;
            er0 = fmaf(df, df, er0);
            xsel0 += ds0;
        }
        {
            const float ld = (mur1 - xsel1) * is1;
            const float sc = fmaf(ds1 - ob1, icv1, rb2_1);
            const float df = ld - sc;
            er1 = fmaf(df, df, er1);
            xsel1 += ds1;
        }

        xt01 += a01; xt23 += a23; xt45 += a45; xt67 += a67; xt89 += a89;
    }

    out[base + lane]          = xsel0;
    out[OUTOFF + base + lane] = er0 * (1.0f / NSTEPS);
    if (has2) {
        out[base + 8 + lane]          = xsel1;
        out[OUTOFF + base + 8 + lane] = er1 * (1.0f / NSTEPS);
    }
}

extern "C" void kernel_launch(void* const* d_in, const int* in_sizes, int n_in,
                              void* d_out, int out_size, void* d_ws, size_t ws_size,
                              hipStream_t stream) {
    const float* z_mean    = (const float*)d_in[0];
    const float* z_log_var = (const float*)d_in[1];
    const float* W1 = (const float*)d_in[2];
    const float* b1 = (const float*)d_in[3];
    const float* W2 = (const float*)d_in[4];
    const float* b2 = (const float*)d_in[5];
    const float* noise = (const float*)d_in[6];
    float* out = (float*)d_out;

    vae_sde_kernel<<<dim3(1280), dim3(256), 0, stream>>>(
        z_mean, z_log_var, W1, b1, W2, b2, noise, out);
}

// Round 12
// 195.578 us; speedup vs baseline: 1.6684x; 1.0682x over previous
//
#include <hip/hip_runtime.h>
#include <math.h>

#define BATCH 512
#define MAXLEN 80
#define LATENT 10
#define HID 64
#define NSTEPS 100
#define DT 0.01f
#define OUTOFF (BATCH * MAXLEN * LATENT)

typedef float v2f __attribute__((ext_vector_type(2)));

__device__ __forceinline__ v2f mkv(float a, float b) { v2f r; r.x = a; r.y = b; return r; }
__device__ __forceinline__ v2f bc(float a) { v2f r; r.x = a; r.y = a; return r; }
__device__ __forceinline__ v2f fma2(v2f a, v2f b, v2f c) { return __builtin_elementwise_fma(a, b, c); }

template <int CTRL>
__device__ __forceinline__ v2f dppadd(v2f x) {
    v2f t;
    t.x = __int_as_float(__builtin_amdgcn_update_dpp(0, __float_as_int(x.x), CTRL, 0xF, 0xF, false));
    t.y = __int_as_float(__builtin_amdgcn_update_dpp(0, __float_as_int(x.y), CTRL, 0xF, 0xF, false));
    return x + t;
}
// all-reduce over 8-lane group: xor1, xor2, mirror
__device__ __forceinline__ v2f allsum(v2f x) {
    x = dppadd<0xB1>(x);    // quad_perm [1,0,3,2]
    x = dppadd<0x4E>(x);    // quad_perm [2,3,0,1]
    x = dppadd<0x141>(x);   // row_half_mirror
    return x;
}

#define HKP(k, xk) { \
    v2f xb = bc(xk); \
    h01 = fma2(xb, w1_##k##_0, h01); h23 = fma2(xb, w1_##k##_1, h23); \
    h45 = fma2(xb, w1_##k##_2, h45); h67 = fma2(xb, w1_##k##_3, h67); }

#define W2P(q, hs) { \
    v2f hb = bc(hs); \
    a01 = fma2(hb, w2_##q##_0, a01); a23 = fma2(hb, w2_##q##_1, a23); \
    a45 = fma2(hb, w2_##q##_2, a45); a67 = fma2(hb, w2_##q##_3, a67); \
    a89 = fma2(hb, w2_##q##_4, a89); }

// Weights come from LDS, not global: ds_read results are NOT rematerializable
// (LDS is mutable memory), so the register allocator must keep them live in
// VGPRs -- it cannot re-emit the load inside the loop the way it did with
// read-only global loads (R5-R11: ~200 remat insts/step, immune to pins).
// R1-R3 showed the compiler happily holds LDS-sourced values in registers
// (it over-hoisted 1400 of them); here we give it 176 floats, which fits the
// waves_per_eu(2,2) budget of ~250 VGPRs.
#define DECLW1(k) \
    v2f w1_##k##_0, w1_##k##_1, w1_##k##_2, w1_##k##_3; { \
        const v2f* r_ = (const v2f*)(sW1p + (k) * HID + j8); \
        w1_##k##_0 = r_[0]; w1_##k##_1 = r_[1]; \
        w1_##k##_2 = r_[2]; w1_##k##_3 = r_[3]; }

#define DECLW2(q) \
    v2f w2_##q##_0, w2_##q##_1, w2_##q##_2, w2_##q##_3, w2_##q##_4; { \
        const v2f* r_ = (const v2f*)(sW2p + (j8 + (q)) * LATENT); \
        w2_##q##_0 = r_[0] * cvt01; w2_##q##_1 = r_[1] * cvt23; \
        w2_##q##_2 = r_[2] * cvt45; w2_##q##_3 = r_[3] * cvt67; \
        w2_##q##_4 = r_[4] * cvt89; }

__global__ __attribute__((amdgpu_waves_per_eu(2, 2))) __launch_bounds__(256)
void vae_sde_kernel(
    const float* __restrict__ z_mean, const float* __restrict__ z_log_var,
    const float* __restrict__ W1, const float* __restrict__ b1,
    const float* __restrict__ W2, const float* __restrict__ b2,
    const float* __restrict__ noise, float* __restrict__ out)
{
    __shared__ __align__(16) float sW[1408];   // 704 W1 | 64 b1 | 640 W2
    __shared__ float sMU[32][LATENT];
    __shared__ float sSG[32][LATENT];

    const int tid  = threadIdx.x;

    // cooperative weight staging (global -> LDS)
    for (int i = tid; i < 704; i += 256) sW[i] = W1[i];
    if (tid < 64) sW[704 + tid] = b1[tid];
    for (int i = tid; i < 640; i += 256) sW[768 + i] = W2[i];

    const int g    = blockIdx.x * 256 + tid;
    const int c    = g >> 3;
    const int lane = tid & 7;
    const int cb   = tid >> 3;
    const int l    = c >> 9;
    const int bb   = c & 511;
    const int base = (bb * MAXLEN + l) * LATENT;
    const bool lp   = (l > 0);
    const bool has2 = (lane < 2);
    const float sqdt = sqrtf(DT);

    float mur0, is0, cw0, icv0, rb2_0, mb0, er0 = 0.f, xsel0;
    float mur1 = 0.f, is1 = 0.f, cw1 = 0.f, icv1 = 0.f, rb2_1 = 0.f,
          mb1 = 0.f, er1 = 0.f, xsel1 = 0.f;

    {
        const int d = lane;
        float zm  = z_mean[base + d];
        float zmp = lp ? z_mean[base - LATENT + d] : 0.f;
        float zv  = z_log_var[base + d];
        float zvp = lp ? z_log_var[base - LATENT + d] : 0.f;
        float mx  = fmaxf(zv, zvp);
        float sg  = mx + log1pf(expf(-fabsf(zv - zvp)));
        float sd  = expf(0.5f * sg);
        float cvv = 0.5f * DT * sd * sd;
        mur0 = zm - zmp; is0 = 1.f / sg; cw0 = sd * sqdt; icv0 = 1.f / cvv;
        rb2_0 = b2[d]; mb0 = fmaf(cvv, rb2_0, mur0 * DT);
        xsel0 = mur0;
        sMU[cb][d] = mur0;
        sSG[cb][d] = sg;
    }
    if (has2) {
        const int d = 8 + lane;
        float zm  = z_mean[base + d];
        float zmp = lp ? z_mean[base - LATENT + d] : 0.f;
        float zv  = z_log_var[base + d];
        float zvp = lp ? z_log_var[base - LATENT + d] : 0.f;
        float mx  = fmaxf(zv, zvp);
        float sg  = mx + log1pf(expf(-fabsf(zv - zvp)));
        float sd  = expf(0.5f * sg);
        float cvv = 0.5f * DT * sd * sd;
        mur1 = zm - zmp; is1 = 1.f / sg; cw1 = sd * sqdt; icv1 = 1.f / cvv;
        rb2_1 = b2[d]; mb1 = fmaf(cvv, rb2_1, mur1 * DT);
        xsel1 = mur1;
        sMU[cb][d] = mur1;
        sSG[cb][d] = sg;
    }
    __syncthreads();

    v2f xt01 = mkv(sMU[cb][0], sMU[cb][1]);
    v2f xt23 = mkv(sMU[cb][2], sMU[cb][3]);
    v2f xt45 = mkv(sMU[cb][4], sMU[cb][5]);
    v2f xt67 = mkv(sMU[cb][6], sMU[cb][7]);
    v2f xt89 = mkv(sMU[cb][8], sMU[cb][9]);
    const v2f cvt01 = mkv(0.5f * DT * expf(sSG[cb][0]), 0.5f * DT * expf(sSG[cb][1]));
    const v2f cvt23 = mkv(0.5f * DT * expf(sSG[cb][2]), 0.5f * DT * expf(sSG[cb][3]));
    const v2f cvt45 = mkv(0.5f * DT * expf(sSG[cb][4]), 0.5f * DT * expf(sSG[cb][5]));
    const v2f cvt67 = mkv(0.5f * DT * expf(sSG[cb][6]), 0.5f * DT * expf(sSG[cb][7]));
    const v2f cvt89 = mkv(0.5f * DT * expf(sSG[cb][8]), 0.5f * DT * expf(sSG[cb][9]));

    const int j8 = lane * 8;
    const float* sW1p = sW;          // [11][64]
    const float* sb1p = sW + 704;    // [64]
    const float* sW2p = sW + 768;    // [64][10]

    v2f b1_0, b1_1, b1_2, b1_3;
    { const v2f* r_ = (const v2f*)(sb1p + j8);
      b1_0 = r_[0]; b1_1 = r_[1]; b1_2 = r_[2]; b1_3 = r_[3]; }

    DECLW1(0) DECLW1(1) DECLW1(2) DECLW1(3) DECLW1(4) DECLW1(5)
    DECLW1(6) DECLW1(7) DECLW1(8) DECLW1(9) DECLW1(10)
    DECLW2(0) DECLW2(1) DECLW2(2) DECLW2(3)
    DECLW2(4) DECLW2(5) DECLW2(6) DECLW2(7)

    const v2f mk01 = mkv(lane == 0 ? 1.f : 0.f, lane == 1 ? 1.f : 0.f);
    const v2f mk23 = mkv(lane == 2 ? 1.f : 0.f, lane == 3 ? 1.f : 0.f);
    const v2f mk45 = mkv(lane == 4 ? 1.f : 0.f, lane == 5 ? 1.f : 0.f);
    const v2f mk67 = mkv(lane == 6 ? 1.f : 0.f, lane == 7 ? 1.f : 0.f);
    const v2f mk89 = mk01;

    const float* np0 = noise + ((size_t)l * NSTEPS * BATCH + bb) * LATENT + lane;
    const float* np1 = np0 + (has2 ? 8 : 0);
    float nz0 = *np0;
    float nz1 = *np1;

    const v2f zero2 = mkv(0.f, 0.f);

    #pragma unroll 1
    for (int s = 0; s < NSTEPS; ++s) {
        const float cu0 = nz0, cu1 = nz1;
        if (s + 1 < NSTEPS) {
            np0 += BATCH * LATENT;
            np1 += BATCH * LATENT;
            nz0 = *np0;
            nz1 = *np1;
        }
        const float tt = (float)(l + s) * DT;

        v2f h01 = fma2(bc(xt01.x), w1_0_0, b1_0);
        v2f h23 = fma2(bc(xt01.x), w1_0_1, b1_1);
        v2f h45 = fma2(bc(xt01.x), w1_0_2, b1_2);
        v2f h67 = fma2(bc(xt01.x), w1_0_3, b1_3);
        HKP(1, xt01.y) HKP(2, xt23.x) HKP(3, xt23.y) HKP(4, xt45.x)
        HKP(5, xt45.y) HKP(6, xt67.x) HKP(7, xt67.y) HKP(8, xt89.x)
        HKP(9, xt89.y) HKP(10, tt)
        h01 = __builtin_elementwise_max(h01, zero2);
        h23 = __builtin_elementwise_max(h23, zero2);
        h45 = __builtin_elementwise_max(h45, zero2);
        h67 = __builtin_elementwise_max(h67, zero2);

        v2f a01 = w2_0_0 * bc(h01.x), a23 = w2_0_1 * bc(h01.x);
        v2f a45 = w2_0_2 * bc(h01.x), a67 = w2_0_3 * bc(h01.x);
        v2f a89 = w2_0_4 * bc(h01.x);
        W2P(1, h01.y) W2P(2, h23.x) W2P(3, h23.y) W2P(4, h45.x)
        W2P(5, h45.y) W2P(6, h67.x) W2P(7, h67.y)

        const float ob0 = fmaf(cw0, cu0, mb0);
        const float ob1 = fmaf(cw1, cu1, mb1);
        a01 = fma2(mk01, bc(ob0), a01);
        a23 = fma2(mk23, bc(ob0), a23);
        a45 = fma2(mk45, bc(ob0), a45);
        a67 = fma2(mk67, bc(ob0), a67);
        a89 = fma2(mk89, bc(ob1), a89);

        a01 = allsum(a01); a23 = allsum(a23); a45 = allsum(a45);
        a67 = allsum(a67); a89 = allsum(a89);

        v2f t = a01 * mk01;
        t = fma2(a23, mk23, t);
        t = fma2(a45, mk45, t);
        t = fma2(a67, mk67, t);
        const float ds0 = t.x + t.y;
        v2f t9 = a89 * mk89;
        const float ds1 = t9.x + t9.y;

        {
            const float ld = (mur0 - xsel0) * is0;
            const float sc = fmaf(ds0 - ob0, icv0, rb2_0);
            const float df = ld - sc;
            er0 = fmaf(df, df, er0);
            xsel0 += ds0;
        }
        {
            const float ld = (mur1 - xsel1) * is1;
            const float sc = fmaf(ds1 - ob1, icv1, rb2_1);
            const float df = ld - sc;
            er1 = fmaf(df, df, er1);
            xsel1 += ds1;
        }

        xt01 += a01; xt23 += a23; xt45 += a45; xt67 += a67; xt89 += a89;
    }

    out[base + lane]          = xsel0;
    out[OUTOFF + base + lane] = er0 * (1.0f / NSTEPS);
    if (has2) {
        out[base + 8 + lane]          = xsel1;
        out[OUTOFF + base + 8 + lane] = er1 * (1.0f / NSTEPS);
    }
}

extern "C" void kernel_launch(void* const* d_in, const int* in_sizes, int n_in,
                              void* d_out, int out_size, void* d_ws, size_t ws_size,
                              hipStream_t stream) {
    const float* z_mean    = (const float*)d_in[0];
    const float* z_log_var = (const float*)d_in[1];
    const float* W1 = (const float*)d_in[2];
    const float* b1 = (const float*)d_in[3];
    const float* W2 = (const float*)d_in[4];
    const float* b2 = (const float*)d_in[5];
    const float* noise = (const float*)d_in[6];
    float* out = (float*)d_out;

    vae_sde_kernel<<<dim3(1280), dim3(256), 0, stream>>>(
        z_mean, z_log_var, W1, b1, W2, b2, noise, out);
}

// Round 13
// 187.886 us; speedup vs baseline: 1.7367x; 1.0409x over previous
//
#include <hip/hip_runtime.h>
#include <math.h>

#define BATCH 512
#define MAXLEN 80
#define LATENT 10
#define HID 64
#define NSTEPS 100
#define DT 0.01f
#define OUTOFF (BATCH * MAXLEN * LATENT)

typedef float v2f __attribute__((ext_vector_type(2)));

__device__ __forceinline__ v2f mkv(float a, float b) { v2f r; r.x = a; r.y = b; return r; }
__device__ __forceinline__ v2f bc(float a) { v2f r; r.x = a; r.y = a; return r; }
__device__ __forceinline__ v2f fma2(v2f a, v2f b, v2f c) { return __builtin_elementwise_fma(a, b, c); }

// Fused DPP butterfly adds: one v_add_f32_dpp per word per stage.
// The update_dpp(0,...) builtin path can expand to mov0 + v_mov_b32_dpp +
// v_add (3 insts/word); writing the fused form directly guarantees 1.
__device__ __forceinline__ float dppadd_x1(float x) {
    float r;
    asm("v_add_f32 %0, %1, %1 quad_perm:[1,0,3,2] row_mask:0xf bank_mask:0xf"
        : "=v"(r) : "v"(x));
    return r;
}
__device__ __forceinline__ float dppadd_x2(float x) {
    float r;
    asm("v_add_f32 %0, %1, %1 quad_perm:[2,3,0,1] row_mask:0xf bank_mask:0xf"
        : "=v"(r) : "v"(x));
    return r;
}
__device__ __forceinline__ float dppadd_m8(float x) {
    float r;
    asm("v_add_f32 %0, %1, %1 row_half_mirror row_mask:0xf bank_mask:0xf"
        : "=v"(r) : "v"(x));
    return r;
}
// all-reduce over 8-lane group: xor1, xor2, half-mirror — 6 insts per pair
__device__ __forceinline__ v2f allsum(v2f x) {
    x.x = dppadd_x1(x.x); x.y = dppadd_x1(x.y);
    x.x = dppadd_x2(x.x); x.y = dppadd_x2(x.y);
    x.x = dppadd_m8(x.x); x.y = dppadd_m8(x.y);
    return x;
}

#define HKP(k, xk) { \
    v2f xb = bc(xk); \
    h01 = fma2(xb, w1_##k##_0, h01); h23 = fma2(xb, w1_##k##_1, h23); \
    h45 = fma2(xb, w1_##k##_2, h45); h67 = fma2(xb, w1_##k##_3, h67); }

#define W2P(q, hs) { \
    v2f hb = bc(hs); \
    a01 = fma2(hb, w2_##q##_0, a01); a23 = fma2(hb, w2_##q##_1, a23); \
    a45 = fma2(hb, w2_##q##_2, a45); a67 = fma2(hb, w2_##q##_3, a67); \
    a89 = fma2(hb, w2_##q##_4, a89); }

#define DECLW1(k) \
    v2f w1_##k##_0, w1_##k##_1, w1_##k##_2, w1_##k##_3; { \
        const v2f* r_ = (const v2f*)&W1[(k) * HID + j8]; \
        w1_##k##_0 = r_[0]; w1_##k##_1 = r_[1]; w1_##k##_2 = r_[2]; w1_##k##_3 = r_[3]; }

#define DECLW2(q) \
    v2f w2_##q##_0, w2_##q##_1, w2_##q##_2, w2_##q##_3, w2_##q##_4; { \
        const v2f* r_ = (const v2f*)(W2 + (j8 + (q)) * LATENT); \
        w2_##q##_0 = r_[0] * cvt01; w2_##q##_1 = r_[1] * cvt23; \
        w2_##q##_2 = r_[2] * cvt45; w2_##q##_3 = r_[3] * cvt67; \
        w2_##q##_4 = r_[4] * cvt89; }

__global__ __launch_bounds__(256, 2) void vae_sde_kernel(
    const float* __restrict__ z_mean, const float* __restrict__ z_log_var,
    const float* __restrict__ W1, const float* __restrict__ b1,
    const float* __restrict__ W2, const float* __restrict__ b2,
    const float* __restrict__ noise, float* __restrict__ out)
{
    __shared__ float sMU[32][LATENT];
    __shared__ float sSG[32][LATENT];

    const int tid  = threadIdx.x;
    const int g    = blockIdx.x * 256 + tid;
    const int c    = g >> 3;
    const int lane = tid & 7;
    const int cb   = tid >> 3;
    const int l    = c >> 9;
    const int bb   = c & 511;
    const int base = (bb * MAXLEN + l) * LATENT;
    const bool lp   = (l > 0);
    const bool has2 = (lane < 2);
    const float sqdt = sqrtf(DT);

    float mur0, is0, cw0, icv0, rb2_0, mb0, er0 = 0.f, xsel0;
    float mur1 = 0.f, is1 = 0.f, cw1 = 0.f, icv1 = 0.f, rb2_1 = 0.f,
          mb1 = 0.f, er1 = 0.f, xsel1 = 0.f;

    {
        const int d = lane;
        float zm  = z_mean[base + d];
        float zmp = lp ? z_mean[base - LATENT + d] : 0.f;
        float zv  = z_log_var[base + d];
        float zvp = lp ? z_log_var[base - LATENT + d] : 0.f;
        float mx  = fmaxf(zv, zvp);
        float sg  = mx + log1pf(expf(-fabsf(zv - zvp)));
        float sd  = expf(0.5f * sg);
        float cvv = 0.5f * DT * sd * sd;
        mur0 = zm - zmp; is0 = 1.f / sg; cw0 = sd * sqdt; icv0 = 1.f / cvv;
        rb2_0 = b2[d]; mb0 = fmaf(cvv, rb2_0, mur0 * DT);
        xsel0 = mur0;
        sMU[cb][d] = mur0;
        sSG[cb][d] = sg;
    }
    if (has2) {
        const int d = 8 + lane;
        float zm  = z_mean[base + d];
        float zmp = lp ? z_mean[base - LATENT + d] : 0.f;
        float zv  = z_log_var[base + d];
        float zvp = lp ? z_log_var[base - LATENT + d] : 0.f;
        float mx  = fmaxf(zv, zvp);
        float sg  = mx + log1pf(expf(-fabsf(zv - zvp)));
        float sd  = expf(0.5f * sg);
        float cvv = 0.5f * DT * sd * sd;
        mur1 = zm - zmp; is1 = 1.f / sg; cw1 = sd * sqdt; icv1 = 1.f / cvv;
        rb2_1 = b2[d]; mb1 = fmaf(cvv, rb2_1, mur1 * DT);
        xsel1 = mur1;
        sMU[cb][d] = mur1;
        sSG[cb][d] = sg;
    }
    __syncthreads();

    v2f xt01 = mkv(sMU[cb][0], sMU[cb][1]);
    v2f xt23 = mkv(sMU[cb][2], sMU[cb][3]);
    v2f xt45 = mkv(sMU[cb][4], sMU[cb][5]);
    v2f xt67 = mkv(sMU[cb][6], sMU[cb][7]);
    v2f xt89 = mkv(sMU[cb][8], sMU[cb][9]);
    const v2f cvt01 = mkv(0.5f * DT * expf(sSG[cb][0]), 0.5f * DT * expf(sSG[cb][1]));
    const v2f cvt23 = mkv(0.5f * DT * expf(sSG[cb][2]), 0.5f * DT * expf(sSG[cb][3]));
    const v2f cvt45 = mkv(0.5f * DT * expf(sSG[cb][4]), 0.5f * DT * expf(sSG[cb][5]));
    const v2f cvt67 = mkv(0.5f * DT * expf(sSG[cb][6]), 0.5f * DT * expf(sSG[cb][7]));
    const v2f cvt89 = mkv(0.5f * DT * expf(sSG[cb][8]), 0.5f * DT * expf(sSG[cb][9]));

    const int j8 = lane * 8;
    v2f b1_0, b1_1, b1_2, b1_3;
    { const v2f* r_ = (const v2f*)&b1[j8]; b1_0 = r_[0]; b1_1 = r_[1]; b1_2 = r_[2]; b1_3 = r_[3]; }

    DECLW1(0) DECLW1(1) DECLW1(2) DECLW1(3) DECLW1(4) DECLW1(5)
    DECLW1(6) DECLW1(7) DECLW1(8) DECLW1(9) DECLW1(10)
    DECLW2(0) DECLW2(1) DECLW2(2) DECLW2(3)
    DECLW2(4) DECLW2(5) DECLW2(6) DECLW2(7)

    const v2f mk01 = mkv(lane == 0 ? 1.f : 0.f, lane == 1 ? 1.f : 0.f);
    const v2f mk23 = mkv(lane == 2 ? 1.f : 0.f, lane == 3 ? 1.f : 0.f);
    const v2f mk45 = mkv(lane == 4 ? 1.f : 0.f, lane == 5 ? 1.f : 0.f);
    const v2f mk67 = mkv(lane == 6 ? 1.f : 0.f, lane == 7 ? 1.f : 0.f);
    const v2f mk89 = mk01;

    const float* np0 = noise + ((size_t)l * NSTEPS * BATCH + bb) * LATENT + lane;
    const float* np1 = np0 + (has2 ? 8 : 0);
    float nz0 = *np0;
    float nz1 = *np1;

    const v2f zero2 = mkv(0.f, 0.f);
    float tt = (float)l * DT;          // carried incrementally (+DT per step)

    #pragma unroll 1
    for (int s = 0; s < NSTEPS; ++s) {
        const float cu0 = nz0, cu1 = nz1;
        if (s + 1 < NSTEPS) {
            np0 += BATCH * LATENT;
            np1 += BATCH * LATENT;
            nz0 = *np0;
            nz1 = *np1;
        }

        v2f h01 = fma2(bc(xt01.x), w1_0_0, b1_0);
        v2f h23 = fma2(bc(xt01.x), w1_0_1, b1_1);
        v2f h45 = fma2(bc(xt01.x), w1_0_2, b1_2);
        v2f h67 = fma2(bc(xt01.x), w1_0_3, b1_3);
        HKP(1, xt01.y) HKP(2, xt23.x) HKP(3, xt23.y) HKP(4, xt45.x)
        HKP(5, xt45.y) HKP(6, xt67.x) HKP(7, xt67.y) HKP(8, xt89.x)
        HKP(9, xt89.y) HKP(10, tt)
        h01 = __builtin_elementwise_max(h01, zero2);
        h23 = __builtin_elementwise_max(h23, zero2);
        h45 = __builtin_elementwise_max(h45, zero2);
        h67 = __builtin_elementwise_max(h67, zero2);

        v2f a01 = w2_0_0 * bc(h01.x), a23 = w2_0_1 * bc(h01.x);
        v2f a45 = w2_0_2 * bc(h01.x), a67 = w2_0_3 * bc(h01.x);
        v2f a89 = w2_0_4 * bc(h01.x);
        W2P(1, h01.y) W2P(2, h23.x) W2P(3, h23.y) W2P(4, h45.x)
        W2P(5, h45.y) W2P(6, h67.x) W2P(7, h67.y)

        const float ob0 = fmaf(cw0, cu0, mb0);
        const float ob1 = fmaf(cw1, cu1, mb1);
        a01 = fma2(mk01, bc(ob0), a01);
        a23 = fma2(mk23, bc(ob0), a23);
        a45 = fma2(mk45, bc(ob0), a45);
        a67 = fma2(mk67, bc(ob0), a67);
        a89 = fma2(mk89, bc(ob1), a89);

        a01 = allsum(a01); a23 = allsum(a23); a45 = allsum(a45);
        a67 = allsum(a67); a89 = allsum(a89);

        v2f t = a01 * mk01;
        t = fma2(a23, mk23, t);
        t = fma2(a45, mk45, t);
        t = fma2(a67, mk67, t);
        const float ds0 = t.x + t.y;
        v2f t9 = a89 * mk89;
        const float ds1 = t9.x + t9.y;

        {
            const float ld = (mur0 - xsel0) * is0;
            const float sc = fmaf(ds0 - ob0, icv0, rb2_0);
            const float df = ld - sc;
            er0 = fmaf(df, df, er0);
            xsel0 += ds0;
        }
        {
            const float ld = (mur1 - xsel1) * is1;
            const float sc = fmaf(ds1 - ob1, icv1, rb2_1);
            const float df = ld - sc;
            er1 = fmaf(df, df, er1);
            xsel1 += ds1;
        }

        xt01 += a01; xt23 += a23; xt45 += a45; xt67 += a67; xt89 += a89;
        tt += DT;
    }

    out[base + lane]          = xsel0;
    out[OUTOFF + base + lane] = er0 * (1.0f / NSTEPS);
    if (has2) {
        out[base + 8 + lane]          = xsel1;
        out[OUTOFF + base + 8 + lane] = er1 * (1.0f / NSTEPS);
    }
}

extern "C" void kernel_launch(void* const* d_in, const int* in_sizes, int n_in,
                              void* d_out, int out_size, void* d_ws, size_t ws_size,
                              hipStream_t stream) {
    const float* z_mean    = (const float*)d_in[0];
    const float* z_log_var = (const float*)d_in[1];
    const float* W1 = (const float*)d_in[2];
    const float* b1 = (const float*)d_in[3];
    const float* W2 = (const float*)d_in[4];
    const float* b2 = (const float*)d_in[5];
    const float* noise = (const float*)d_in[6];
    float* out = (float*)d_out;

    vae_sde_kernel<<<dim3(1280), dim3(256), 0, stream>>>(
        z_mean, z_log_var, W1, b1, W2, b2, noise, out);
}

// Round 14
// 94.897 us; speedup vs baseline: 3.4385x; 1.9799x over previous
//
#include <hip/hip_runtime.h>
#include <math.h>

#define BATCH 512
#define MAXLEN 80
#define LATENT 10
#define HID 64
#define NSTEPS 100
#define DT 0.01f
#define OUTOFF (BATCH * MAXLEN * LATENT)

typedef __attribute__((ext_vector_type(8)))  short s16x8;   // 8 bf16 = 4 VGPRs
typedef __attribute__((ext_vector_type(16))) float f32x16;
typedef __attribute__((ext_vector_type(4)))  int   i32x4;

__device__ __forceinline__ int cvtpk(float lo, float hi) {
    int r;
    asm("v_cvt_pk_bf16_f32 %0, %1, %2" : "=v"(r) : "v"(lo), "v"(hi));
    return r;
}
__device__ __forceinline__ s16x8 mk8(int a, int b, int c, int d) {
    i32x4 v; v.x = a; v.y = b; v.z = c; v.w = d;
    return __builtin_bit_cast(s16x8, v);
}

// Per-owned-dim setup. j=0..3 -> d=4*hi+j ; j=4,5 -> d=8,9 (hi=1's j4,5 are
// valid-data dummies, never stored).
#define SETUP(J, DD) \
    float mur##J, is##J, cv##J, cw##J, mb##J, xs##J, er##J; { \
        const int dd_ = (DD); \
        float zm = z_mean[base + dd_]; \
        float zp = lp ? z_mean[base - LATENT + dd_] : 0.f; \
        float zv = z_log_var[base + dd_]; \
        float zq = lp ? z_log_var[base - LATENT + dd_] : 0.f; \
        float mx = fmaxf(zv, zq); \
        float sg = mx + log1pf(expf(-fabsf(zv - zq))); \
        float sd = expf(0.5f * sg); \
        mur##J = zm - zp; is##J = 1.f / sg; cv##J = 0.5f * DT * sd * sd; \
        cw##J = sd * 0.1f; mb##J = mur##J * DT; \
        xs##J = mur##J; er##J = 0.f; }

// epilogue: err uses xt BEFORE update; sc includes b2 (via C-in of L2 MFMA)
#define EP(J, CU, SC) { \
    const float sc_ = (SC); \
    const float ld_ = (mur##J - xs##J) * is##J; \
    const float df_ = ld_ - sc_; \
    er##J = fmaf(df_, df_, er##J); \
    const float ob_ = fmaf(cw##J, (CU), mb##J); \
    xs##J = xs##J + fmaf(cv##J, sc_, ob_); }

__global__ __launch_bounds__(64) void vae_sde_kernel(
    const float* __restrict__ z_mean, const float* __restrict__ z_log_var,
    const float* __restrict__ W1, const float* __restrict__ b1,
    const float* __restrict__ W2, const float* __restrict__ b2,
    const float* __restrict__ noise, float* __restrict__ out)
{
    const int lane = threadIdx.x;      // 0..63
    const int hi   = lane >> 5;        // k-block selector
    const int ci   = lane & 31;        // chain within wave == MFMA col
    const int wv   = blockIdx.x;       // one wave per block
    const int c    = wv * 32 + ci;     // chain id (l uniform per wave)
    const int l    = c >> 9;
    const int bb   = c & 511;
    const int base = (bb * MAXLEN + l) * LATENT;
    const bool lp  = (l > 0);

    // ---- owned dims (D2 C-layout: row=(reg&3)+8*(reg>>2)+4*hi, col=ci) ----
    const int d0 = 4 * hi, d1v = d0 + 1, d2v = d0 + 2, d3v = d0 + 3;

    SETUP(0, d0) SETUP(1, d1v) SETUP(2, d2v) SETUP(3, d3v)
    SETUP(4, 8)  SETUP(5, 9)

    // ---- static zero / b2 C-in fragments ----
    f32x16 z16;
    #pragma unroll
    for (int i = 0; i < 16; ++i) z16[i] = 0.f;

    f32x16 b2c;
    #pragma unroll
    for (int rr = 0; rr < 16; ++rr) {
        const int row = (rr & 3) + 8 * (rr >> 2) + 4 * hi;
        b2c[rr] = (row < LATENT) ? b2[row] : 0.f;
    }

    // ---- W1^T A-fragments (K-ext: k=0..9 xt, k=10 t-row, k=11 ONE->b1) ----
    // A layout 32x32x16: lane holds m=lane&31, k = 8*(lane>>5) + i
    const int k0 = 8 * hi;
    s16x8 a1a, a1b;
    {
        float v[8], w[8];
        #pragma unroll
        for (int i = 0; i < 8; ++i) {
            const int k = k0 + i;
            v[i] = (k <= 10) ? W1[k * HID + ci]
                 : (k == 11 ? b1[ci] : 0.f);
            w[i] = (k <= 10) ? W1[k * HID + 32 + ci]
                 : (k == 11 ? b1[32 + ci] : 0.f);
        }
        a1a = mk8(cvtpk(v[0], v[1]), cvtpk(v[2], v[3]), cvtpk(v[4], v[5]), cvtpk(v[6], v[7]));
        a1b = mk8(cvtpk(w[0], w[1]), cvtpk(w[2], w[3]), cvtpk(w[4], w[5]), cvtpk(w[6], w[7]));
    }

    // ---- W2^T A-fragments, 4 K-slices of 16 (rows m>=10 zero-padded) ----
    s16x8 a20, a21, a22, a23;
    #define MKA2(Q, VAR) { \
        float v[8]; \
        _Pragma("unroll") \
        for (int i = 0; i < 8; ++i) { \
            const int k = 16 * (Q) + k0 + i; \
            v[i] = (ci < LATENT) ? W2[k * LATENT + ci] : 0.f; \
        } \
        VAR = mk8(cvtpk(v[0], v[1]), cvtpk(v[2], v[3]), cvtpk(v[4], v[5]), cvtpk(v[6], v[7])); }
    MKA2(0, a20) MKA2(1, a21) MKA2(2, a22) MKA2(3, a23)
    #undef MKA2

    // ---- noise pointers (imm-offset trick; d=8,9 from unshifted base) ----
    const float* nb  = noise + ((size_t)l * NSTEPS * BATCH + bb) * LATENT;
    const float* nbs = nb + 4 * hi;
    float nz0 = nbs[0], nz1 = nbs[1], nz2 = nbs[2], nz3 = nbs[3];
    float nz4 = nb[8],  nz5 = nb[9];

    #pragma unroll 1
    for (int s = 0; s < NSTEPS; ++s) {
        const float cu0 = nz0, cu1 = nz1, cu2 = nz2, cu3 = nz3, cu4 = nz4, cu5 = nz5;
        if (s + 1 < NSTEPS) {
            nbs += BATCH * LATENT; nb += BATCH * LATENT;
            nz0 = nbs[0]; nz1 = nbs[1]; nz2 = nbs[2]; nz3 = nbs[3];
            nz4 = nb[8];  nz5 = nb[9];
        }

        // ---- build X B-fragment: B[k][chain], k = 8*hi + 2w..2w+1 ----
        const float tt = (float)(l + s) * DT;
        const int wt = cvtpk(tt, 1.0f);          // (t, ONE)
        const int p0 = cvtpk(xs0, xs1);          // hi=0:(d0,d1) hi=1:(d4,d5)
        const int p1 = cvtpk(xs2, xs3);          // (d2,d3)/(d6,d7)
        const int p2 = cvtpk(xs4, xs5);          // (d8,d9)/junk(unused)
        const int q0 = __shfl_xor(p0, 32);
        const int q1 = __shfl_xor(p1, 32);
        const int q2 = __shfl_xor(p2, 32);
        const s16x8 bx = mk8(hi ? q2 : p0,       // k 0,1  | 8,9
                             hi ? wt : p1,       // k 2,3  | t,1
                             hi ? 0  : q0,       // k 4,5  | 0,0
                             hi ? 0  : q1);      // k 6,7  | 0,0

        // ---- layer 1: H[hid, chain] = W1^T @ X  (+ bias via ONE row) ----
        f32x16 h0v = __builtin_amdgcn_mfma_f32_32x32x16_bf16(a1a, bx, z16, 0, 0, 0);
        f32x16 h1v = __builtin_amdgcn_mfma_f32_32x32x16_bf16(a1b, bx, z16, 0, 0, 0);
        h0v = __builtin_elementwise_max(h0v, z16);   // relu
        h1v = __builtin_elementwise_max(h1v, z16);

        // ---- H -> B2 fragments (4 K-slices of 16 hid rows each) ----
        // own rows: reg r -> row (r&3)+8*(r>>2)+4*hi
        const int cA0 = cvtpk(h0v[0],  h0v[1]),  cA1 = cvtpk(h0v[2],  h0v[3]);
        const int cB0 = cvtpk(h0v[4],  h0v[5]),  cB1 = cvtpk(h0v[6],  h0v[7]);
        const int cC0 = cvtpk(h0v[8],  h0v[9]),  cC1 = cvtpk(h0v[10], h0v[11]);
        const int cD0 = cvtpk(h0v[12], h0v[13]), cD1 = cvtpk(h0v[14], h0v[15]);
        const int sA0 = __shfl_xor(cA0, 32), sA1 = __shfl_xor(cA1, 32);
        const int sB0 = __shfl_xor(cB0, 32), sB1 = __shfl_xor(cB1, 32);
        const int sC0 = __shfl_xor(cC0, 32), sC1 = __shfl_xor(cC1, 32);
        const int sD0 = __shfl_xor(cD0, 32), sD1 = __shfl_xor(cD1, 32);
        const s16x8 f0 = hi ? mk8(sB0, sB1, cB0, cB1) : mk8(cA0, cA1, sA0, sA1);
        const s16x8 f1 = hi ? mk8(sD0, sD1, cD0, cD1) : mk8(cC0, cC1, sC0, sC1);

        const int eA0 = cvtpk(h1v[0],  h1v[1]),  eA1 = cvtpk(h1v[2],  h1v[3]);
        const int eB0 = cvtpk(h1v[4],  h1v[5]),  eB1 = cvtpk(h1v[6],  h1v[7]);
        const int eC0 = cvtpk(h1v[8],  h1v[9]),  eC1 = cvtpk(h1v[10], h1v[11]);
        const int eD0 = cvtpk(h1v[12], h1v[13]), eD1 = cvtpk(h1v[14], h1v[15]);
        const int tA0 = __shfl_xor(eA0, 32), tA1 = __shfl_xor(eA1, 32);
        const int tB0 = __shfl_xor(eB0, 32), tB1 = __shfl_xor(eB1, 32);
        const int tC0 = __shfl_xor(eC0, 32), tC1 = __shfl_xor(eC1, 32);
        const int tD0 = __shfl_xor(eD0, 32), tD1 = __shfl_xor(eD1, 32);
        const s16x8 f2 = hi ? mk8(tB0, tB1, eB0, eB1) : mk8(eA0, eA1, tA0, tA1);
        const s16x8 f3 = hi ? mk8(tD0, tD1, eD0, eD1) : mk8(eC0, eC1, tC0, tC1);

        // ---- layer 2: S[lat, chain] = W2^T @ H + b2 (b2 via C-in) ----
        f32x16 d2 = __builtin_amdgcn_mfma_f32_32x32x16_bf16(a20, f0, b2c, 0, 0, 0);
        d2 = __builtin_amdgcn_mfma_f32_32x32x16_bf16(a21, f1, d2, 0, 0, 0);
        d2 = __builtin_amdgcn_mfma_f32_32x32x16_bf16(a22, f2, d2, 0, 0, 0);
        d2 = __builtin_amdgcn_mfma_f32_32x32x16_bf16(a23, f3, d2, 0, 0, 0);

        // ---- epilogue (f32): owned sc = d2[0..5]; hi=1 j4,5 dummies sc=0 ----
        EP(0, cu0, d2[0]) EP(1, cu1, d2[1]) EP(2, cu2, d2[2])
        EP(3, cu3, d2[3]) EP(4, cu4, d2[4]) EP(5, cu5, d2[5])
    }

    // ---- store (hi=1's j4,5 are dummies -> only hi=0 stores d=8,9) ----
    const float esc = 1.0f / NSTEPS;
    out[base + d0]  = xs0; out[OUTOFF + base + d0]  = er0 * esc;
    out[base + d1v] = xs1; out[OUTOFF + base + d1v] = er1 * esc;
    out[base + d2v] = xs2; out[OUTOFF + base + d2v] = er2 * esc;
    out[base + d3v] = xs3; out[OUTOFF + base + d3v] = er3 * esc;
    if (hi == 0) {
        out[base + 8] = xs4; out[OUTOFF + base + 8] = er4 * esc;
        out[base + 9] = xs5; out[OUTOFF + base + 9] = er5 * esc;
    }
}

extern "C" void kernel_launch(void* const* d_in, const int* in_sizes, int n_in,
                              void* d_out, int out_size, void* d_ws, size_t ws_size,
                              hipStream_t stream) {
    const float* z_mean    = (const float*)d_in[0];
    const float* z_log_var = (const float*)d_in[1];
    const float* W1 = (const float*)d_in[2];
    const float* b1 = (const float*)d_in[3];
    const float* W2 = (const float*)d_in[4];
    const float* b2 = (const float*)d_in[5];
    const float* noise = (const float*)d_in[6];
    float* out = (float*)d_out;

    // 40960 chains / 32 per wave = 1280 waves, one per 64-thread block
    vae_sde_kernel<<<dim3(1280), dim3(64), 0, stream>>>(
        z_mean, z_log_var, W1, b1, W2, b2, noise, out);
}

// Round 15
// 81.814 us; speedup vs baseline: 3.9884x; 1.1599x over previous
//
#include <hip/hip_runtime.h>
#include <math.h>

#define BATCH 512
#define MAXLEN 80
#define LATENT 10
#define HID 64
#define NSTEPS 100
#define DT 0.01f
#define OUTOFF (BATCH * MAXLEN * LATENT)

typedef __attribute__((ext_vector_type(8)))  short s16x8;   // 8 bf16 = 4 VGPRs
typedef __attribute__((ext_vector_type(16))) float f32x16;
typedef __attribute__((ext_vector_type(4)))  int   i32x4;

__device__ __forceinline__ int cvtpk(float lo, float hi) {
    int r;
    asm("v_cvt_pk_bf16_f32 %0, %1, %2" : "=v"(r) : "v"(lo), "v"(hi));
    return r;
}
__device__ __forceinline__ s16x8 mk8(int a, int b, int c, int d) {
    i32x4 v; v.x = a; v.y = b; v.z = c; v.w = d;
    return __builtin_bit_cast(s16x8, v);
}

#define SETUP(J, DD) \
    float mur##J, is##J, cv##J, cw##J, mb##J, xs##J, er##J; { \
        const int dd_ = (DD); \
        float zm = z_mean[base + dd_]; \
        float zp = lp ? z_mean[base - LATENT + dd_] : 0.f; \
        float zv = z_log_var[base + dd_]; \
        float zq = lp ? z_log_var[base - LATENT + dd_] : 0.f; \
        float mx = fmaxf(zv, zq); \
        float sg = mx + log1pf(expf(-fabsf(zv - zq))); \
        float sd = expf(0.5f * sg); \
        mur##J = zm - zp; is##J = 1.f / sg; cv##J = 0.5f * DT * sd * sd; \
        cw##J = sd * 0.1f; mb##J = mur##J * DT; \
        xs##J = mur##J; er##J = 0.f; }

#define EP(J, CU, SC) { \
    const float sc_ = (SC); \
    const float ld_ = (mur##J - xs##J) * is##J; \
    const float df_ = ld_ - sc_; \
    er##J = fmaf(df_, df_, er##J); \
    const float ob_ = fmaf(cw##J, (CU), mb##J); \
    xs##J = xs##J + fmaf(cv##J, sc_, ob_); }

__global__ __launch_bounds__(64) void vae_sde_kernel(
    const float* __restrict__ z_mean, const float* __restrict__ z_log_var,
    const float* __restrict__ W1, const float* __restrict__ b1,
    const float* __restrict__ W2, const float* __restrict__ b2,
    const float* __restrict__ noise, float* __restrict__ out)
{
    const int lane = threadIdx.x;      // 0..63
    const int hi   = lane >> 5;        // k-half selector
    const int ci   = lane & 31;        // chain within wave == MFMA col
    const int wv   = blockIdx.x;
    const int c    = wv * 32 + ci;     // chain id (l uniform per wave)
    const int l    = c >> 9;
    const int bb   = c & 511;
    const int base = (bb * MAXLEN + l) * LATENT;
    const bool lp  = (l > 0);

    // owned dims: d = 4*hi + {0..3}; both halves also carry dims 8,9
    // (hi=1's copies are non-stored dummies - their sc rows are W2-padding)
    const int d0 = 4 * hi, d1v = d0 + 1, d2v = d0 + 2, d3v = d0 + 3;

    SETUP(0, d0) SETUP(1, d1v) SETUP(2, d2v) SETUP(3, d3v)
    SETUP(4, 8)  SETUP(5, 9)

    f32x16 z16;
    #pragma unroll
    for (int i = 0; i < 16; ++i) z16[i] = 0.f;

    f32x16 b2c;
    #pragma unroll
    for (int rr = 0; rr < 16; ++rr) {
        const int row = (rr & 3) + 8 * (rr >> 2) + 4 * hi;
        b2c[rr] = (row < LATENT) ? b2[rr < 8 ? row : 0] * (row < LATENT) : 0.f;
    }
    // (rewrite plainly to avoid cleverness)
    #pragma unroll
    for (int rr = 0; rr < 16; ++rr) {
        const int row = (rr & 3) + 8 * (rr >> 2) + 4 * hi;
        b2c[rr] = (row < LATENT) ? b2[row] : 0.f;
    }

    // ---- W1^T A-fragments, K-PERMUTED so X B-build needs no shuffles ----
    // K-slot -> input row:  hi=0: {0,1,2,3, 8,9, Z,Z}   (lane-owned dims)
    //                       hi=1: {4,5,6,7, 10(t), ONE(b1), Z,Z}
    s16x8 a1a, a1b;
    {
        float v[8], w[8];
        #pragma unroll
        for (int i = 0; i < 8; ++i) {
            int row;               // -1 => b1, -2 => zero
            if (i < 4)      row = 4 * hi + i;
            else if (i == 4) row = hi ? 10 : 8;
            else if (i == 5) row = hi ? -1 : 9;
            else             row = -2;
            v[i] = (row >= 0) ? W1[row * HID + ci]      : (row == -1 ? b1[ci]      : 0.f);
            w[i] = (row >= 0) ? W1[row * HID + 32 + ci] : (row == -1 ? b1[32 + ci] : 0.f);
        }
        a1a = mk8(cvtpk(v[0], v[1]), cvtpk(v[2], v[3]), cvtpk(v[4], v[5]), cvtpk(v[6], v[7]));
        a1b = mk8(cvtpk(w[0], w[1]), cvtpk(w[2], w[3]), cvtpk(w[4], w[5]), cvtpk(w[6], w[7]));
    }

    // ---- W2^T A-fragments, K-PERMUTED to match H's MFMA-D register order:
    // slot (q,hi,i) -> hidden row 16q + 8*(i>>2) + 4*hi + (i&3)
    // => B-fragments are cvtpk of D-regs IN ORDER (zero shuffles).
    s16x8 a20, a21, a22, a23;
    #define MKA2(Q, VAR) { \
        float v[8]; \
        _Pragma("unroll") \
        for (int i = 0; i < 8; ++i) { \
            const int row = 16 * (Q) + 8 * (i >> 2) + 4 * hi + (i & 3); \
            v[i] = (ci < LATENT) ? W2[row * LATENT + ci] : 0.f; \
        } \
        VAR = mk8(cvtpk(v[0], v[1]), cvtpk(v[2], v[3]), cvtpk(v[4], v[5]), cvtpk(v[6], v[7])); }
    MKA2(0, a20) MKA2(1, a21) MKA2(2, a22) MKA2(3, a23)
    #undef MKA2

    // ---- noise: 3 x float2 per step (8-byte aligned; row stride 40 B) ----
    const float* nb = noise + ((size_t)l * NSTEPS * BATCH + bb) * LATENT;
    float2 nA = *(const float2*)(nb + 4 * hi);
    float2 nB = *(const float2*)(nb + 4 * hi + 2);
    float2 nC = *(const float2*)(nb + 8);

    float tt = (float)l * DT;

    #pragma unroll 1
    for (int s = 0; s < NSTEPS; ++s) {
        const float cu0 = nA.x, cu1 = nA.y, cu2 = nB.x, cu3 = nB.y;
        const float cu4 = nC.x, cu5 = nC.y;
        if (s + 1 < NSTEPS) {
            nb += BATCH * LATENT;
            nA = *(const float2*)(nb + 4 * hi);
            nB = *(const float2*)(nb + 4 * hi + 2);
            nC = *(const float2*)(nb + 8);
        }

        // ---- X B-fragment: all slots lane-owned (K-permuted W1) ----
        const int w0 = cvtpk(xs0, xs1);
        const int w1 = cvtpk(xs2, xs3);
        const int w2 = hi ? cvtpk(tt, 1.0f) : cvtpk(xs4, xs5);
        const s16x8 bx = mk8(w0, w1, w2, 0);

        // ---- layer 1 ----
        f32x16 h0v = __builtin_amdgcn_mfma_f32_32x32x16_bf16(a1a, bx, z16, 0, 0, 0);
        f32x16 h1v = __builtin_amdgcn_mfma_f32_32x32x16_bf16(a1b, bx, z16, 0, 0, 0);
        h0v = __builtin_elementwise_max(h0v, z16);
        h1v = __builtin_elementwise_max(h1v, z16);

        // ---- H -> B fragments: D-regs in order, zero shuffles ----
        const s16x8 f0 = mk8(cvtpk(h0v[0],  h0v[1]),  cvtpk(h0v[2],  h0v[3]),
                             cvtpk(h0v[4],  h0v[5]),  cvtpk(h0v[6],  h0v[7]));
        const s16x8 f1 = mk8(cvtpk(h0v[8],  h0v[9]),  cvtpk(h0v[10], h0v[11]),
                             cvtpk(h0v[12], h0v[13]), cvtpk(h0v[14], h0v[15]));
        const s16x8 f2 = mk8(cvtpk(h1v[0],  h1v[1]),  cvtpk(h1v[2],  h1v[3]),
                             cvtpk(h1v[4],  h1v[5]),  cvtpk(h1v[6],  h1v[7]));
        const s16x8 f3 = mk8(cvtpk(h1v[8],  h1v[9]),  cvtpk(h1v[10], h1v[11]),
                             cvtpk(h1v[12], h1v[13]), cvtpk(h1v[14], h1v[15]));

        // ---- layer 2: two independent MFMA chains, then merge ----
        f32x16 dA = __builtin_amdgcn_mfma_f32_32x32x16_bf16(a20, f0, b2c, 0, 0, 0);
        f32x16 dB = __builtin_amdgcn_mfma_f32_32x32x16_bf16(a21, f1, z16, 0, 0, 0);
        dA = __builtin_amdgcn_mfma_f32_32x32x16_bf16(a22, f2, dA, 0, 0, 0);
        dB = __builtin_amdgcn_mfma_f32_32x32x16_bf16(a23, f3, dB, 0, 0, 0);

        const float sc0 = dA[0] + dB[0];
        const float sc1 = dA[1] + dB[1];
        const float sc2 = dA[2] + dB[2];
        const float sc3 = dA[3] + dB[3];
        const float sc4 = dA[4] + dB[4];
        const float sc5 = dA[5] + dB[5];

        EP(0, cu0, sc0) EP(1, cu1, sc1) EP(2, cu2, sc2)
        EP(3, cu3, sc3) EP(4, cu4, sc4) EP(5, cu5, sc5)

        tt += DT;
    }

    const float esc = 1.0f / NSTEPS;
    out[base + d0]  = xs0; out[OUTOFF + base + d0]  = er0 * esc;
    out[base + d1v] = xs1; out[OUTOFF + base + d1v] = er1 * esc;
    out[base + d2v] = xs2; out[OUTOFF + base + d2v] = er2 * esc;
    out[base + d3v] = xs3; out[OUTOFF + base + d3v] = er3 * esc;
    if (hi == 0) {
        out[base + 8] = xs4; out[OUTOFF + base + 8] = er4 * esc;
        out[base + 9] = xs5; out[OUTOFF + base + 9] = er5 * esc;
    }
}

extern "C" void kernel_launch(void* const* d_in, const int* in_sizes, int n_in,
                              void* d_out, int out_size, void* d_ws, size_t ws_size,
                              hipStream_t stream) {
    const float* z_mean    = (const float*)d_in[0];
    const float* z_log_var = (const float*)d_in[1];
    const float* W1 = (const float*)d_in[2];
    const float* b1 = (const float*)d_in[3];
    const float* W2 = (const float*)d_in[4];
    const float* b2 = (const float*)d_in[5];
    const float* noise = (const float*)d_in[6];
    float* out = (float*)d_out;

    vae_sde_kernel<<<dim3(1280), dim3(64), 0, stream>>>(
        z_mean, z_log_var, W1, b1, W2, b2, noise, out);
}

// Round 16
// 70.606 us; speedup vs baseline: 4.6215x; 1.1587x over previous
//
#include <hip/hip_runtime.h>
#include <math.h>

#define BATCH 512
#define MAXLEN 80
#define LATENT 10
#define HID 64
#define NSTEPS 100
#define DT 0.01f
#define OUTOFF (BATCH * MAXLEN * LATENT)

typedef __attribute__((ext_vector_type(8))) short s16x8;   // 8 bf16 = 4 VGPRs
typedef __attribute__((ext_vector_type(4))) float f32x4;
typedef __attribute__((ext_vector_type(4))) int   i32x4;

__device__ __forceinline__ int cvtpk(float lo, float hi) {
    int r;
    asm("v_cvt_pk_bf16_f32 %0, %1, %2" : "=v"(r) : "v"(lo), "v"(hi));
    return r;
}
__device__ __forceinline__ s16x8 mk8(int a, int b, int c, int d) {
    i32x4 v; v.x = a; v.y = b; v.z = c; v.w = d;
    return __builtin_bit_cast(s16x8, v);
}

// lane owns latent dims db+j (db = 4*(lane>>4)); dims >= 10 are finite dummies
#define SETUP(J) \
    float mur##J, is##J, cv##J, cw##J, mb##J, xs##J, er##J; { \
        const int dd_ = (db + (J) < LATENT) ? db + (J) : 0; \
        float zm = z_mean[base + dd_]; \
        float zp = lp ? z_mean[base - LATENT + dd_] : 0.f; \
        float zv = z_log_var[base + dd_]; \
        float zq = lp ? z_log_var[base - LATENT + dd_] : 0.f; \
        float mx = fmaxf(zv, zq); \
        float sg = mx + log1pf(expf(-fabsf(zv - zq))); \
        float sd = expf(0.5f * sg); \
        mur##J = zm - zp; is##J = 1.f / sg; cv##J = 0.5f * DT * sd * sd; \
        cw##J = sd * 0.1f; mb##J = mur##J * DT; \
        xs##J = mur##J; er##J = 0.f; }

#define EP(J, CU, SC) { \
    const float sc_ = (SC); \
    const float ld_ = (mur##J - xs##J) * is##J; \
    const float df_ = ld_ - sc_; \
    er##J = fmaf(df_, df_, er##J); \
    const float ob_ = fmaf(cw##J, (CU), mb##J); \
    xs##J = xs##J + fmaf(cv##J, sc_, ob_); }

__global__ __launch_bounds__(64) void vae_sde_kernel(
    const float* __restrict__ z_mean, const float* __restrict__ z_log_var,
    const float* __restrict__ W1, const float* __restrict__ b1,
    const float* __restrict__ W2, const float* __restrict__ b2,
    const float* __restrict__ noise, float* __restrict__ out)
{
    const int lane = threadIdx.x;      // 0..63
    const int kg   = lane >> 4;        // K-group 0..3
    const int ci   = lane & 15;        // chain col (B/D); latent-m (A2); hid-m (A1)
    const int c    = blockIdx.x * 16 + ci;   // chain id (16 chains/wave)
    const int l    = c >> 9;
    const int bb   = c & 511;
    const int base = (bb * MAXLEN + l) * LATENT;
    const bool lp  = (l > 0);
    const int  db  = kg * 4;           // owned latent dims db..db+3
    const bool kg3 = (kg == 3);

    SETUP(0) SETUP(1) SETUP(2) SETUP(3)

    f32x4 z4;
    z4[0] = 0.f; z4[1] = 0.f; z4[2] = 0.f; z4[3] = 0.f;

    // b2 C-in: D reg r -> latent row db + r
    f32x4 b2c;
    #pragma unroll
    for (int r = 0; r < 4; ++r)
        b2c[r] = (db + r < LATENT) ? b2[db + r] : 0.f;

    // ---- W1^T A-fragments (4 M-tiles of 16 hid rows), K-permuted:
    // slot k = kg*8+i -> input row: i<4: db+i (if <10); i==4: t-row (kg3);
    // i==5: ONE->b1 (kg3); else zero.  Lane's A row = hid 16*mt + ci.
    #define MKA1(MT, VAR) \
        s16x8 VAR; { \
            const int col = 16 * (MT) + ci; \
            float v[8]; \
            _Pragma("unroll") \
            for (int i = 0; i < 8; ++i) { \
                int row; \
                if (i < 4)       row = (db + i < LATENT) ? db + i : -2; \
                else if (i == 4) row = kg3 ? 10 : -2; \
                else if (i == 5) row = kg3 ? -1 : -2; \
                else             row = -2; \
                v[i] = (row >= 0) ? W1[row * HID + col] \
                     : (row == -1 ? b1[col] : 0.f); \
            } \
            VAR = mk8(cvtpk(v[0], v[1]), cvtpk(v[2], v[3]), \
                      cvtpk(v[4], v[5]), cvtpk(v[6], v[7])); }
    MKA1(0, a10) MKA1(1, a11) MKA1(2, a12) MKA1(3, a13)
    #undef MKA1

    // ---- W2^T A-fragments (2 K-chunks of 32 hid), K-permuted to match H's
    // D-reg order: slot (kg,i) of chunk q -> hid row 16*(2q+(i>>2)) + db + (i&3)
    #define MKA2(Q, VAR) \
        s16x8 VAR; { \
            float v[8]; \
            _Pragma("unroll") \
            for (int i = 0; i < 8; ++i) { \
                const int hr = 16 * (2 * (Q) + (i >> 2)) + db + (i & 3); \
                v[i] = (ci < LATENT) ? W2[hr * LATENT + ci] : 0.f; \
            } \
            VAR = mk8(cvtpk(v[0], v[1]), cvtpk(v[2], v[3]), \
                      cvtpk(v[4], v[5]), cvtpk(v[6], v[7])); }
    MKA2(0, a20) MKA2(1, a21)
    #undef MKA2

    // ---- noise: lane's dims db..db+3 as 2 x float2 (kg=2 re-reads 8,9;
    // kg=3 reads dims 0,1 as finite dummies - never OOB) ----
    const int offA = (kg == 0) ? 0 : (kg == 1) ? 4 : 8;
    const int offB = (kg == 0) ? 2 : (kg == 1) ? 6 : 8;
    const float* nb = noise + ((size_t)l * NSTEPS * BATCH + bb) * LATENT;
    float2 nA = *(const float2*)(nb + offA);
    float2 nB = *(const float2*)(nb + offB);

    float tt = (float)l * DT;

    #pragma unroll 1
    for (int s = 0; s < NSTEPS; ++s) {
        const float cu0 = nA.x, cu1 = nA.y, cu2 = nB.x, cu3 = nB.y;
        if (s + 1 < NSTEPS) {
            nb += BATCH * LATENT;
            nA = *(const float2*)(nb + offA);
            nB = *(const float2*)(nb + offB);
        }

        // ---- X B-fragment: all slots lane-owned (K-permuted W1) ----
        const int w0 = cvtpk(xs0, xs1);
        const int w1 = cvtpk(xs2, xs3);      // kg=2,3 junk x zero-A = 0
        const int w2 = kg3 ? cvtpk(tt, 1.0f) : 0;
        const s16x8 bx = mk8(w0, w1, w2, 0);

        // ---- layer 1: 4 independent MFMAs ----
        f32x4 h0 = __builtin_amdgcn_mfma_f32_16x16x32_bf16(a10, bx, z4, 0, 0, 0);
        f32x4 h1 = __builtin_amdgcn_mfma_f32_16x16x32_bf16(a11, bx, z4, 0, 0, 0);
        f32x4 h2 = __builtin_amdgcn_mfma_f32_16x16x32_bf16(a12, bx, z4, 0, 0, 0);
        f32x4 h3 = __builtin_amdgcn_mfma_f32_16x16x32_bf16(a13, bx, z4, 0, 0, 0);
        h0 = __builtin_elementwise_max(h0, z4);
        h1 = __builtin_elementwise_max(h1, z4);
        h2 = __builtin_elementwise_max(h2, z4);
        h3 = __builtin_elementwise_max(h3, z4);

        // ---- H -> B fragments: D-regs in order, zero shuffles ----
        const s16x8 f0 = mk8(cvtpk(h0[0], h0[1]), cvtpk(h0[2], h0[3]),
                             cvtpk(h1[0], h1[1]), cvtpk(h1[2], h1[3]));
        const s16x8 f1 = mk8(cvtpk(h2[0], h2[1]), cvtpk(h2[2], h2[3]),
                             cvtpk(h3[0], h3[1]), cvtpk(h3[2], h3[3]));

        // ---- layer 2: 2-MFMA chain, b2 via C-in ----
        f32x4 d2 = __builtin_amdgcn_mfma_f32_16x16x32_bf16(a20, f0, b2c, 0, 0, 0);
        d2 = __builtin_amdgcn_mfma_f32_16x16x32_bf16(a21, f1, d2, 0, 0, 0);

        // ---- epilogue (f32) on lane's 4 dims ----
        EP(0, cu0, d2[0]) EP(1, cu1, d2[1]) EP(2, cu2, d2[2]) EP(3, cu3, d2[3])

        tt += DT;
    }

    // ---- store owned dims (float2, 8B aligned) ----
    const float esc = 1.0f / NSTEPS;
    if (db < 8) {
        *(float2*)(out + base + db)              = make_float2(xs0, xs1);
        *(float2*)(out + base + db + 2)          = make_float2(xs2, xs3);
        *(float2*)(out + OUTOFF + base + db)     = make_float2(er0 * esc, er1 * esc);
        *(float2*)(out + OUTOFF + base + db + 2) = make_float2(er2 * esc, er3 * esc);
    } else if (kg == 2) {
        *(float2*)(out + base + 8)          = make_float2(xs0, xs1);
        *(float2*)(out + OUTOFF + base + 8) = make_float2(er0 * esc, er1 * esc);
    }
}

extern "C" void kernel_launch(void* const* d_in, const int* in_sizes, int n_in,
                              void* d_out, int out_size, void* d_ws, size_t ws_size,
                              hipStream_t stream) {
    const float* z_mean    = (const float*)d_in[0];
    const float* z_log_var = (const float*)d_in[1];
    const float* W1 = (const float*)d_in[2];
    const float* b1 = (const float*)d_in[3];
    const float* W2 = (const float*)d_in[4];
    const float* b2 = (const float*)d_in[5];
    const float* noise = (const float*)d_in[6];
    float* out = (float*)d_out;

    // 40960 chains / 16 per wave = 2560 waves (2.5 per SIMD)
    vae_sde_kernel<<<dim3(2560), dim3(64), 0, stream>>>(
        z_mean, z_log_var, W1, b1, W2, b2, noise, out);
}

// Round 17
// 65.816 us; speedup vs baseline: 4.9579x; 1.0728x over previous
//
#include <hip/hip_runtime.h>
#include <math.h>

#define BATCH 512
#define MAXLEN 80
#define LATENT 10
#define HID 64
#define NSTEPS 100
#define DT 0.01f
#define OUTOFF (BATCH * MAXLEN * LATENT)

typedef __attribute__((ext_vector_type(8))) short s16x8;   // 8 bf16 = 4 VGPRs
typedef __attribute__((ext_vector_type(4))) float f32x4;
typedef __attribute__((ext_vector_type(4))) int   i32x4;
typedef __attribute__((ext_vector_type(2))) float v2f;

__device__ __forceinline__ int cvtpk(float lo, float hi) {
    int r;
    asm("v_cvt_pk_bf16_f32 %0, %1, %2" : "=v"(r) : "v"(lo), "v"(hi));
    return r;
}
// ReLU on a packed pair of bf16: positive bf16 values are order-isomorphic
// to positive int16 (sign bit clear); negatives have sign bit set -> max_i16
// with 0 zeroes them. -0.0 (0x8000) -> 0. Equivalent to relu-then-convert.
__device__ __forceinline__ int pkrelu(int x, int z) {
    int r;
    asm("v_pk_max_i16 %0, %1, %2" : "=v"(r) : "v"(x), "v"(z));
    return r;
}
__device__ __forceinline__ s16x8 mk8(int a, int b, int c, int d) {
    i32x4 v; v.x = a; v.y = b; v.z = c; v.w = d;
    return __builtin_bit_cast(s16x8, v);
}
__device__ __forceinline__ v2f mkv(float a, float b) { v2f r; r.x = a; r.y = b; return r; }
__device__ __forceinline__ v2f fma2(v2f a, v2f b, v2f c) { return __builtin_elementwise_fma(a, b, c); }

// scalar per-dim setup (runs once; packed into v2f pairs after)
#define SETUP(J) \
    float mur##J, is##J, cv##J, cw##J, mb##J; { \
        const int dd_ = (db + (J) < LATENT) ? db + (J) : 0; \
        float zm = z_mean[base + dd_]; \
        float zp = lp ? z_mean[base - LATENT + dd_] : 0.f; \
        float zv = z_log_var[base + dd_]; \
        float zq = lp ? z_log_var[base - LATENT + dd_] : 0.f; \
        float mx = fmaxf(zv, zq); \
        float sg = mx + log1pf(expf(-fabsf(zv - zq))); \
        float sd = expf(0.5f * sg); \
        mur##J = zm - zp; is##J = 1.f / sg; cv##J = 0.5f * DT * sd * sd; \
        cw##J = sd * 0.1f; mb##J = mur##J * DT; }

// packed EP on a dim pair: identical per-component op order to R16 scalar EP
#define EPP(P, CU, SC) { \
    const v2f sc_ = (SC); \
    const v2f t1_ = mur##P - xs##P; \
    const v2f ld_ = t1_ * is##P; \
    const v2f df_ = ld_ - sc_; \
    er##P = fma2(df_, df_, er##P); \
    const v2f ob_ = fma2(cw##P, (CU), mb##P); \
    xs##P = xs##P + fma2(cv##P, sc_, ob_); }

__global__ __launch_bounds__(64) void vae_sde_kernel(
    const float* __restrict__ z_mean, const float* __restrict__ z_log_var,
    const float* __restrict__ W1, const float* __restrict__ b1,
    const float* __restrict__ W2, const float* __restrict__ b2,
    const float* __restrict__ noise, float* __restrict__ out)
{
    const int lane = threadIdx.x;      // 0..63
    const int kg   = lane >> 4;        // K-group 0..3
    const int ci   = lane & 15;        // chain col (B/D); latent-m (A2); hid-m (A1)
    const int c    = blockIdx.x * 16 + ci;   // chain id (16 chains/wave)
    const int l    = c >> 9;
    const int bb   = c & 511;
    const int base = (bb * MAXLEN + l) * LATENT;
    const bool lp  = (l > 0);
    const int  db  = kg * 4;           // owned latent dims db..db+3
    const bool kg3 = (kg == 3);

    SETUP(0) SETUP(1) SETUP(2) SETUP(3)

    // pack per-dim params into pairs
    const v2f mur01 = mkv(mur0, mur1), mur23 = mkv(mur2, mur3);
    const v2f is01  = mkv(is0,  is1),  is23  = mkv(is2,  is3);
    const v2f cv01  = mkv(cv0,  cv1),  cv23  = mkv(cv2,  cv3);
    const v2f cw01  = mkv(cw0,  cw1),  cw23  = mkv(cw2,  cw3);
    const v2f mb01  = mkv(mb0,  mb1),  mb23  = mkv(mb2,  mb3);
    v2f xs01 = mur01, xs23 = mur23;
    v2f er01 = mkv(0.f, 0.f), er23 = mkv(0.f, 0.f);

    f32x4 z4;
    z4[0] = 0.f; z4[1] = 0.f; z4[2] = 0.f; z4[3] = 0.f;
    const int zpk = 0;   // zero reg for pkrelu

    // b2 C-in: D reg r -> latent row db + r
    f32x4 b2c;
    #pragma unroll
    for (int r = 0; r < 4; ++r)
        b2c[r] = (db + r < LATENT) ? b2[db + r] : 0.f;

    // ---- W1^T A-fragments (4 M-tiles of 16 hid rows), K-permuted:
    // slot k = kg*8+i -> input row: i<4: db+i (if <10); i==4: t-row (kg3);
    // i==5: ONE->b1 (kg3); else zero.  Lane's A row = hid 16*mt + ci.
    #define MKA1(MT, VAR) \
        s16x8 VAR; { \
            const int col = 16 * (MT) + ci; \
            float v[8]; \
            _Pragma("unroll") \
            for (int i = 0; i < 8; ++i) { \
                int row; \
                if (i < 4)       row = (db + i < LATENT) ? db + i : -2; \
                else if (i == 4) row = kg3 ? 10 : -2; \
                else if (i == 5) row = kg3 ? -1 : -2; \
                else             row = -2; \
                v[i] = (row >= 0) ? W1[row * HID + col] \
                     : (row == -1 ? b1[col] : 0.f); \
            } \
            VAR = mk8(cvtpk(v[0], v[1]), cvtpk(v[2], v[3]), \
                      cvtpk(v[4], v[5]), cvtpk(v[6], v[7])); }
    MKA1(0, a10) MKA1(1, a11) MKA1(2, a12) MKA1(3, a13)
    #undef MKA1

    // ---- W2^T A-fragments (2 K-chunks of 32 hid), K-permuted to match H's
    // D-reg order: slot (kg,i) of chunk q -> hid row 16*(2q+(i>>2)) + db + (i&3)
    #define MKA2(Q, VAR) \
        s16x8 VAR; { \
            float v[8]; \
            _Pragma("unroll") \
            for (int i = 0; i < 8; ++i) { \
                const int hr = 16 * (2 * (Q) + (i >> 2)) + db + (i & 3); \
                v[i] = (ci < LATENT) ? W2[hr * LATENT + ci] : 0.f; \
            } \
            VAR = mk8(cvtpk(v[0], v[1]), cvtpk(v[2], v[3]), \
                      cvtpk(v[4], v[5]), cvtpk(v[6], v[7])); }
    MKA2(0, a20) MKA2(1, a21)
    #undef MKA2

    // ---- noise: lane's dims db..db+3 as 2 x float2 ----
    const int offA = (kg == 0) ? 0 : (kg == 1) ? 4 : 8;
    const int offB = (kg == 0) ? 2 : (kg == 1) ? 6 : 8;
    const float* nb = noise + ((size_t)l * NSTEPS * BATCH + bb) * LATENT;
    float2 nA = *(const float2*)(nb + offA);
    float2 nB = *(const float2*)(nb + offB);

    float tt = (float)l * DT;

    #pragma unroll 1
    for (int s = 0; s < NSTEPS; ++s) {
        const v2f cu01 = mkv(nA.x, nA.y);
        const v2f cu23 = mkv(nB.x, nB.y);
        if (s + 1 < NSTEPS) {
            nb += BATCH * LATENT;
            nA = *(const float2*)(nb + offA);
            nB = *(const float2*)(nb + offB);
        }

        // ---- X B-fragment: all slots lane-owned (K-permuted W1) ----
        const int w0 = cvtpk(xs01.x, xs01.y);
        const int w1 = cvtpk(xs23.x, xs23.y);   // kg>=2 junk x zero-A = 0
        const int w2 = kg3 ? cvtpk(tt, 1.0f) : 0;
        const s16x8 bx = mk8(w0, w1, w2, 0);

        // ---- layer 1: 4 independent MFMAs (no f32 relu; relu in bf16) ----
        const f32x4 h0 = __builtin_amdgcn_mfma_f32_16x16x32_bf16(a10, bx, z4, 0, 0, 0);
        const f32x4 h1 = __builtin_amdgcn_mfma_f32_16x16x32_bf16(a11, bx, z4, 0, 0, 0);
        const f32x4 h2 = __builtin_amdgcn_mfma_f32_16x16x32_bf16(a12, bx, z4, 0, 0, 0);
        const f32x4 h3 = __builtin_amdgcn_mfma_f32_16x16x32_bf16(a13, bx, z4, 0, 0, 0);

        // ---- H -> B fragments: cvtpk then packed bf16 relu, zero shuffles ----
        const s16x8 f0 = mk8(pkrelu(cvtpk(h0[0], h0[1]), zpk),
                             pkrelu(cvtpk(h0[2], h0[3]), zpk),
                             pkrelu(cvtpk(h1[0], h1[1]), zpk),
                             pkrelu(cvtpk(h1[2], h1[3]), zpk));
        const s16x8 f1 = mk8(pkrelu(cvtpk(h2[0], h2[1]), zpk),
                             pkrelu(cvtpk(h2[2], h2[3]), zpk),
                             pkrelu(cvtpk(h3[0], h3[1]), zpk),
                             pkrelu(cvtpk(h3[2], h3[3]), zpk));

        // ---- layer 2: 2 independent MFMAs, merge with packed adds ----
        const f32x4 dA = __builtin_amdgcn_mfma_f32_16x16x32_bf16(a20, f0, b2c, 0, 0, 0);
        const f32x4 dB = __builtin_amdgcn_mfma_f32_16x16x32_bf16(a21, f1, z4, 0, 0, 0);
        const v2f sc01 = mkv(dA[0], dA[1]) + mkv(dB[0], dB[1]);
        const v2f sc23 = mkv(dA[2], dA[3]) + mkv(dB[2], dB[3]);

        // ---- packed epilogue on lane's 4 dims ----
        EPP(01, cu01, sc01)
        EPP(23, cu23, sc23)

        tt += DT;
    }

    // ---- store owned dims (float2, 8B aligned) ----
    const v2f e01 = er01 * (1.0f / NSTEPS);
    const v2f e23 = er23 * (1.0f / NSTEPS);
    if (db < 8) {
        *(float2*)(out + base + db)              = make_float2(xs01.x, xs01.y);
        *(float2*)(out + base + db + 2)          = make_float2(xs23.x, xs23.y);
        *(float2*)(out + OUTOFF + base + db)     = make_float2(e01.x, e01.y);
        *(float2*)(out + OUTOFF + base + db + 2) = make_float2(e23.x, e23.y);
    } else if (kg == 2) {
        *(float2*)(out + base + 8)          = make_float2(xs01.x, xs01.y);
        *(float2*)(out + OUTOFF + base + 8) = make_float2(e01.x, e01.y);
    }
}

extern "C" void kernel_launch(void* const* d_in, const int* in_sizes, int n_in,
                              void* d_out, int out_size, void* d_ws, size_t ws_size,
                              hipStream_t stream) {
    const float* z_mean    = (const float*)d_in[0];
    const float* z_log_var = (const float*)d_in[1];
    const float* W1 = (const float*)d_in[2];
    const float* b1 = (const float*)d_in[3];
    const float* W2 = (const float*)d_in[4];
    const float* b2 = (const float*)d_in[5];
    const float* noise = (const float*)d_in[6];
    float* out = (float*)d_out;

    // 40960 chains / 16 per wave = 2560 waves (2.5 per SIMD)
    vae_sde_kernel<<<dim3(2560), dim3(64), 0, stream>>>(
        z_mean, z_log_var, W1, b1, W2, b2, noise, out);
}

// Round 18
// 59.923 us; speedup vs baseline: 5.4454x; 1.0983x over previous
//
#include <hip/hip_runtime.h>
#include <math.h>

#define BATCH 512
#define MAXLEN 80
#define LATENT 10
#define HID 64
#define NSTEPS 100
#define DT 0.01f
#define OUTOFF (BATCH * MAXLEN * LATENT)
#define NSTRIDE (BATCH * LATENT)

typedef __attribute__((ext_vector_type(8))) short s16x8;   // 8 bf16 = 4 VGPRs
typedef __attribute__((ext_vector_type(4))) float f32x4;
typedef __attribute__((ext_vector_type(4))) int   i32x4;
typedef __attribute__((ext_vector_type(2))) float v2f;

__device__ __forceinline__ int cvtpk(float lo, float hi) {
    int r;
    asm("v_cvt_pk_bf16_f32 %0, %1, %2" : "=v"(r) : "v"(lo), "v"(hi));
    return r;
}
// ReLU on packed bf16 pair (positive bf16 order-isomorphic to int16)
__device__ __forceinline__ int pkrelu(int x, int z) {
    int r;
    asm("v_pk_max_i16 %0, %1, %2" : "=v"(r) : "v"(x), "v"(z));
    return r;
}
__device__ __forceinline__ s16x8 mk8(int a, int b, int c, int d) {
    i32x4 v; v.x = a; v.y = b; v.z = c; v.w = d;
    return __builtin_bit_cast(s16x8, v);
}
__device__ __forceinline__ v2f mkv(float a, float b) { v2f r; r.x = a; r.y = b; return r; }
__device__ __forceinline__ v2f fma2(v2f a, v2f b, v2f c) { return __builtin_elementwise_fma(a, b, c); }

#define SETUP(J) \
    float mur##J, is##J, cv##J, cw##J, mb##J; { \
        const int dd_ = (db + (J) < LATENT) ? db + (J) : 0; \
        float zm = z_mean[base + dd_]; \
        float zp = lp ? z_mean[base - LATENT + dd_] : 0.f; \
        float zv = z_log_var[base + dd_]; \
        float zq = lp ? z_log_var[base - LATENT + dd_] : 0.f; \
        float mx = fmaxf(zv, zq); \
        float sg = mx + log1pf(expf(-fabsf(zv - zq))); \
        float sd = expf(0.5f * sg); \
        mur##J = zm - zp; is##J = 1.f / sg; cv##J = 0.5f * DT * sd * sd; \
        cw##J = sd * 0.1f; mb##J = mur##J * DT; }

#define EPP(P, CU, SC) { \
    const v2f sc_ = (SC); \
    const v2f t1_ = mur##P - xs##P; \
    const v2f ld_ = t1_ * is##P; \
    const v2f df_ = ld_ - sc_; \
    er##P = fma2(df_, df_, er##P); \
    const v2f ob_ = fma2(cw##P, (CU), mb##P); \
    xs##P = xs##P + fma2(cv##P, sc_, ob_); }

// one SDE step consuming noise buffers (NAv,NBv); optionally prefetching
// 4-steps-ahead into the same buffers (DO_PF is a literal 0/1)
#define STEPM(NAv, NBv, DO_PF) { \
    const v2f cu01 = mkv(NAv.x, NAv.y); \
    const v2f cu23 = mkv(NBv.x, NBv.y); \
    if (DO_PF) { \
        NAv = *(const float2*)(nbp + offA); \
        NBv = *(const float2*)(nbp + offB); \
        nbp += NSTRIDE; \
    } \
    const int w0 = cvtpk(xs01.x, xs01.y); \
    const int w1 = cvtpk(xs23.x, xs23.y); \
    const int w2 = kg3 ? cvtpk(tt, 1.0f) : 0; \
    const s16x8 bx = mk8(w0, w1, w2, 0); \
    const f32x4 h0 = __builtin_amdgcn_mfma_f32_16x16x32_bf16(a10, bx, z4, 0, 0, 0); \
    const f32x4 h1 = __builtin_amdgcn_mfma_f32_16x16x32_bf16(a11, bx, z4, 0, 0, 0); \
    const f32x4 h2 = __builtin_amdgcn_mfma_f32_16x16x32_bf16(a12, bx, z4, 0, 0, 0); \
    const f32x4 h3 = __builtin_amdgcn_mfma_f32_16x16x32_bf16(a13, bx, z4, 0, 0, 0); \
    const s16x8 f0 = mk8(pkrelu(cvtpk(h0[0], h0[1]), zpk), \
                         pkrelu(cvtpk(h0[2], h0[3]), zpk), \
                         pkrelu(cvtpk(h1[0], h1[1]), zpk), \
                         pkrelu(cvtpk(h1[2], h1[3]), zpk)); \
    const s16x8 f1 = mk8(pkrelu(cvtpk(h2[0], h2[1]), zpk), \
                         pkrelu(cvtpk(h2[2], h2[3]), zpk), \
                         pkrelu(cvtpk(h3[0], h3[1]), zpk), \
                         pkrelu(cvtpk(h3[2], h3[3]), zpk)); \
    const f32x4 dA = __builtin_amdgcn_mfma_f32_16x16x32_bf16(a20, f0, b2c, 0, 0, 0); \
    const f32x4 dB = __builtin_amdgcn_mfma_f32_16x16x32_bf16(a21, f1, z4, 0, 0, 0); \
    const v2f sc01 = mkv(dA[0], dA[1]) + mkv(dB[0], dB[1]); \
    const v2f sc23 = mkv(dA[2], dA[3]) + mkv(dB[2], dB[3]); \
    EPP(01, cu01, sc01) \
    EPP(23, cu23, sc23) \
    tt += DT; }

__global__ __launch_bounds__(64) void vae_sde_kernel(
    const float* __restrict__ z_mean, const float* __restrict__ z_log_var,
    const float* __restrict__ W1, const float* __restrict__ b1,
    const float* __restrict__ W2, const float* __restrict__ b2,
    const float* __restrict__ noise, float* __restrict__ out)
{
    const int lane = threadIdx.x;      // 0..63
    const int kg   = lane >> 4;        // K-group 0..3
    const int ci   = lane & 15;        // chain col
    const int c    = blockIdx.x * 16 + ci;
    const int l    = c >> 9;
    const int bb   = c & 511;
    const int base = (bb * MAXLEN + l) * LATENT;
    const bool lp  = (l > 0);
    const int  db  = kg * 4;
    const bool kg3 = (kg == 3);

    SETUP(0) SETUP(1) SETUP(2) SETUP(3)

    const v2f mur01 = mkv(mur0, mur1), mur23 = mkv(mur2, mur3);
    const v2f is01  = mkv(is0,  is1),  is23  = mkv(is2,  is3);
    const v2f cv01  = mkv(cv0,  cv1),  cv23  = mkv(cv2,  cv3);
    const v2f cw01  = mkv(cw0,  cw1),  cw23  = mkv(cw2,  cw3);
    const v2f mb01  = mkv(mb0,  mb1),  mb23  = mkv(mb2,  mb3);
    v2f xs01 = mur01, xs23 = mur23;
    v2f er01 = mkv(0.f, 0.f), er23 = mkv(0.f, 0.f);

    f32x4 z4;
    z4[0] = 0.f; z4[1] = 0.f; z4[2] = 0.f; z4[3] = 0.f;
    const int zpk = 0;

    f32x4 b2c;
    #pragma unroll
    for (int r = 0; r < 4; ++r)
        b2c[r] = (db + r < LATENT) ? b2[db + r] : 0.f;

    #define MKA1(MT, VAR) \
        s16x8 VAR; { \
            const int col = 16 * (MT) + ci; \
            float v[8]; \
            _Pragma("unroll") \
            for (int i = 0; i < 8; ++i) { \
                int row; \
                if (i < 4)       row = (db + i < LATENT) ? db + i : -2; \
                else if (i == 4) row = kg3 ? 10 : -2; \
                else if (i == 5) row = kg3 ? -1 : -2; \
                else             row = -2; \
                v[i] = (row >= 0) ? W1[row * HID + col] \
                     : (row == -1 ? b1[col] : 0.f); \
            } \
            VAR = mk8(cvtpk(v[0], v[1]), cvtpk(v[2], v[3]), \
                      cvtpk(v[4], v[5]), cvtpk(v[6], v[7])); }
    MKA1(0, a10) MKA1(1, a11) MKA1(2, a12) MKA1(3, a13)
    #undef MKA1

    #define MKA2(Q, VAR) \
        s16x8 VAR; { \
            float v[8]; \
            _Pragma("unroll") \
            for (int i = 0; i < 8; ++i) { \
                const int hr = 16 * (2 * (Q) + (i >> 2)) + db + (i & 3); \
                v[i] = (ci < LATENT) ? W2[hr * LATENT + ci] : 0.f; \
            } \
            VAR = mk8(cvtpk(v[0], v[1]), cvtpk(v[2], v[3]), \
                      cvtpk(v[4], v[5]), cvtpk(v[6], v[7])); }
    MKA2(0, a20) MKA2(1, a21)
    #undef MKA2

    // ---- noise: 4-step-deep prefetch (HBM latency ~900cy ≫ 1-step window;
    // R17 counters: VALUBusy 34%, wall 1580cy/step vs 266cy issue =>
    // noise-load latency was the bound) ----
    const int offA = (kg == 0) ? 0 : (kg == 1) ? 4 : 8;
    const int offB = (kg == 0) ? 2 : (kg == 1) ? 6 : 8;
    const float* nb = noise + ((size_t)l * NSTEPS * BATCH + bb) * LATENT;

    float2 nA0 = *(const float2*)(nb + offA);
    float2 nB0 = *(const float2*)(nb + offB);
    float2 nA1 = *(const float2*)(nb + NSTRIDE + offA);
    float2 nB1 = *(const float2*)(nb + NSTRIDE + offB);
    float2 nA2 = *(const float2*)(nb + 2 * NSTRIDE + offA);
    float2 nB2 = *(const float2*)(nb + 2 * NSTRIDE + offB);
    float2 nA3 = *(const float2*)(nb + 3 * NSTRIDE + offA);
    float2 nB3 = *(const float2*)(nb + 3 * NSTRIDE + offB);
    const float* nbp = nb + 4 * NSTRIDE;   // next row to prefetch (s+4)

    float tt = (float)l * DT;

    // 24 iterations x 4 steps (s=0..95), prefetching s+4 each step
    #pragma unroll 1
    for (int it = 0; it < 24; ++it) {
        STEPM(nA0, nB0, 1)
        STEPM(nA1, nB1, 1)
        STEPM(nA2, nB2, 1)
        STEPM(nA3, nB3, 1)
    }
    // epilogue: s=96..99, no prefetch
    STEPM(nA0, nB0, 0)
    STEPM(nA1, nB1, 0)
    STEPM(nA2, nB2, 0)
    STEPM(nA3, nB3, 0)

    const v2f e01 = er01 * (1.0f / NSTEPS);
    const v2f e23 = er23 * (1.0f / NSTEPS);
    if (db < 8) {
        *(float2*)(out + base + db)              = make_float2(xs01.x, xs01.y);
        *(float2*)(out + base + db + 2)          = make_float2(xs23.x, xs23.y);
        *(float2*)(out + OUTOFF + base + db)     = make_float2(e01.x, e01.y);
        *(float2*)(out + OUTOFF + base + db + 2) = make_float2(e23.x, e23.y);
    } else if (kg == 2) {
        *(float2*)(out + base + 8)          = make_float2(xs01.x, xs01.y);
        *(float2*)(out + OUTOFF + base + 8) = make_float2(e01.x, e01.y);
    }
}

extern "C" void kernel_launch(void* const* d_in, const int* in_sizes, int n_in,
                              void* d_out, int out_size, void* d_ws, size_t ws_size,
                              hipStream_t stream) {
    const float* z_mean    = (const float*)d_in[0];
    const float* z_log_var = (const float*)d_in[1];
    const float* W1 = (const float*)d_in[2];
    const float* b1 = (const float*)d_in[3];
    const float* W2 = (const float*)d_in[4];
    const float* b2 = (const float*)d_in[5];
    const float* noise = (const float*)d_in[6];
    float* out = (float*)d_out;

    vae_sde_kernel<<<dim3(2560), dim3(64), 0, stream>>>(
        z_mean, z_log_var, W1, b1, W2, b2, noise, out);
}